// Round 13
// baseline (151.758 us; speedup 1.0000x reference)
//
#include <hip/hip_runtime.h>
#include <hip/hip_bf16.h>
#include <math.h>

typedef unsigned short u16;
typedef __attribute__((ext_vector_type(8))) __bf16 bf16x8;
typedef __attribute__((ext_vector_type(4))) float f32x4;
typedef __attribute__((ext_vector_type(16))) float f32x16;
typedef __attribute__((ext_vector_type(8))) unsigned short u16x8;
typedef __attribute__((ext_vector_type(4))) unsigned int u32x4;
typedef __attribute__((ext_vector_type(2))) unsigned int u32x2;

// ---------- helpers ----------
__device__ __forceinline__ u16 f2bf(float f) {
  union { float f; unsigned u; } x; x.f = f;
  unsigned r = x.u + 0x7fffu + ((x.u >> 16) & 1u);   // RNE
  return (u16)(r >> 16);
}

__device__ __forceinline__ void gload16(const u16* g, u16* l) {
  __builtin_amdgcn_global_load_lds(
      (const __attribute__((address_space(1))) void*)g,
      (__attribute__((address_space(3))) void*)l, 16, 0, 0);
}

#define MFMA16(a, b, c) __builtin_amdgcn_mfma_f32_16x16x32_bf16((a), (b), (c), 0, 0, 0)
#define MFMA32(a, b, c) __builtin_amdgcn_mfma_f32_32x32x16_bf16((a), (b), (c), 0, 0, 0)

// Q pre-scale: 1/sqrt(64) * log2(e)  (softmax done in exp2 domain)
#define QSCALE 0.18033688011112043f

// ---------- merged cast fp32 -> bf16 (x, Wqkv, Wo in one launch) ----------
__global__ __launch_bounds__(256) void cast_all_kernel(
    const float* __restrict__ x, const float* __restrict__ wqkv,
    const float* __restrict__ wo, u16* __restrict__ xb,
    u16* __restrict__ wqb, u16* __restrict__ wob) {
  int i = blockIdx.x * 256 + threadIdx.x;   // in float4 units
  const float* src; u16* dst;
  if (i < 1048576)      { src = x;    dst = xb;  }
  else if (i < 1835008) { src = wqkv; dst = wqb; i -= 1048576; }
  else                  { src = wo;   dst = wob; i -= 1835008; }
  f32x4 v = *(const f32x4*)(src + (size_t)i * 4);
  u16 o0 = f2bf(v[0]), o1 = f2bf(v[1]), o2 = f2bf(v[2]), o3 = f2bf(v[3]);
  unsigned lo = (unsigned)o0 | ((unsigned)o1 << 16);
  unsigned hi = (unsigned)o2 | ((unsigned)o3 << 16);
  ((unsigned*)dst)[(size_t)i * 2] = lo;
  ((unsigned*)dst)[(size_t)i * 2 + 1] = hi;
}

// ---------- shared 128x128 / BK=64 bf16 GEMM main loop (C = A * B^T) ----------
__device__ __forceinline__ void gemm_bt_128(
    const u16* __restrict__ A, const u16* __restrict__ B, int K, int m0, int n0,
    u16* As, u16* Bs, f32x4 acc[4][4]) {
  const int tid = threadIdx.x;
  const int lane = tid & 63;
  const int wr = tid >> 7;
  const int wc = (tid >> 6) & 1;
  for (int k0 = 0; k0 < K; k0 += 64) {
    #pragma unroll
    for (int it = 0; it < 4; ++it) {
      int c = it * 256 + tid;
      int row = c >> 3;
      int ko = (c & 7) << 3;
      gload16(A + (size_t)(m0 + row) * K + (k0 + ko), As + c * 8);
      gload16(B + (size_t)(n0 + row) * K + (k0 + ko), Bs + c * 8);
    }
    __syncthreads();
    #pragma unroll
    for (int kk = 0; kk < 2; ++kk) {
      bf16x8 a[4], b[4];
      #pragma unroll
      for (int m = 0; m < 4; ++m)
        a[m] = *(const bf16x8*)(As + ((wr * 64 + m * 16 + (lane & 15)) * 64 +
                                      kk * 32 + ((lane >> 4) << 3)));
      #pragma unroll
      for (int n = 0; n < 4; ++n)
        b[n] = *(const bf16x8*)(Bs + ((wc * 64 + n * 16 + (lane & 15)) * 64 +
                                      kk * 32 + ((lane >> 4) << 3)));
      #pragma unroll
      for (int m = 0; m < 4; ++m)
        #pragma unroll
        for (int n = 0; n < 4; ++n)
          acc[m][n] = MFMA16(a[m], b[n], acc[m][n]);
    }
    __syncthreads();
  }
}

// ---------- GEMM1: qkv = x @ Wqkv^T + b, scatter q/k/v to [B,nh,C,64] bf16 ----------
// Epilogue through LDS: stage bf16 C-tile (stride 136), then u16x8 stores.
__global__ __launch_bounds__(256) void gemm_qkv_kernel(
    const u16* __restrict__ X, const u16* __restrict__ W, const float* __restrict__ bias,
    u16* __restrict__ Qb, u16* __restrict__ Kb, u16* __restrict__ Vb) {
  __shared__ __align__(16) u16 S[17408];   // 2x 128x64 staging, reused as 128x136 C
  f32x4 acc[4][4];
  #pragma unroll
  for (int m = 0; m < 4; ++m)
    #pragma unroll
    for (int n = 0; n < 4; ++n) acc[m][n] = (f32x4){0.f, 0.f, 0.f, 0.f};
  const int m0 = blockIdx.y * 128;
  const int n0 = blockIdx.x * 128;
  gemm_bt_128(X, W, 1024, m0, n0, S, S + 8192, acc);

  const int tid = threadIdx.x;
  const int lane = tid & 63;
  const int wr = tid >> 7, wc = (tid >> 6) & 1;
  const int which = n0 >> 10;                       // 0=Q 1=K 2=V (block-uniform)
  const float qs = (which == 0) ? QSCALE : 1.0f;
  u16* __restrict__ dst = (which == 0) ? Qb : (which == 1 ? Kb : Vb);

  // stage C-tile (bias + scale applied) into LDS
  #pragma unroll
  for (int m = 0; m < 4; ++m)
    #pragma unroll
    for (int n = 0; n < 4; ++n)
      #pragma unroll
      for (int j = 0; j < 4; ++j) {
        int row = wr * 64 + m * 16 + ((lane >> 4) << 2) + j;
        int col = wc * 64 + n * 16 + (lane & 15);
        float v = (acc[m][n][j] + bias[n0 + col]) * qs;
        S[row * 136 + col] = f2bf(v);
      }
  __syncthreads();

  // vectorized store: 2048 16B-chunks, 8 per thread
  #pragma unroll
  for (int i = 0; i < 8; ++i) {
    int c = i * 256 + tid;
    int row = c >> 4, ch = c & 15;
    u16x8 val = *(const u16x8*)(S + row * 136 + ch * 8);
    int grow = m0 + row;
    int bb = grow >> 11, q = grow & 2047;
    int gcol = n0 + ch * 8;
    int h = (gcol >> 6) & 15, d0 = gcol & 63;
    *(u16x8*)(dst + ((size_t)((bb * 16 + h) * 2048 + q)) * 64 + d0) = val;
  }
}

// ---------- GEMM2: out = attn @ Wo^T + b (fp32 out), 64x128 tile ----------
__global__ __launch_bounds__(256) void gemm_out_kernel(
    const u16* __restrict__ Ain, const u16* __restrict__ W, const float* __restrict__ bias,
    float* __restrict__ out) {
  __shared__ __align__(16) u16 As[64 * 64];
  __shared__ __align__(16) u16 Bs[128 * 64];
  const int tid = threadIdx.x;
  const int lane = tid & 63;
  const int wc = tid >> 6;                 // wave -> 32-col group
  const int m0 = blockIdx.y * 64;
  const int n0 = blockIdx.x * 128;
  f32x4 acc[4][2] = {};
  for (int k0 = 0; k0 < 1024; k0 += 64) {
    #pragma unroll
    for (int it = 0; it < 2; ++it) {
      int c = it * 256 + tid;
      gload16(Ain + (size_t)(m0 + (c >> 3)) * 1024 + k0 + ((c & 7) << 3), As + c * 8);
    }
    #pragma unroll
    for (int it = 0; it < 4; ++it) {
      int c = it * 256 + tid;
      gload16(W + (size_t)(n0 + (c >> 3)) * 1024 + k0 + ((c & 7) << 3), Bs + c * 8);
    }
    __syncthreads();
    #pragma unroll
    for (int kk = 0; kk < 2; ++kk) {
      bf16x8 a[4], b[2];
      #pragma unroll
      for (int m = 0; m < 4; ++m)
        a[m] = *(const bf16x8*)(As + ((m * 16 + (lane & 15)) * 64 +
                                      kk * 32 + ((lane >> 4) << 3)));
      #pragma unroll
      for (int n = 0; n < 2; ++n)
        b[n] = *(const bf16x8*)(Bs + ((wc * 32 + n * 16 + (lane & 15)) * 64 +
                                      kk * 32 + ((lane >> 4) << 3)));
      #pragma unroll
      for (int m = 0; m < 4; ++m)
        #pragma unroll
        for (int n = 0; n < 2; ++n)
          acc[m][n] = MFMA16(a[m], b[n], acc[m][n]);
    }
    __syncthreads();
  }
  #pragma unroll
  for (int m = 0; m < 4; ++m)
    #pragma unroll
    for (int n = 0; n < 2; ++n)
      #pragma unroll
      for (int j = 0; j < 4; ++j) {
        int row = m0 + m * 16 + ((lane >> 4) << 2) + j;
        int col = n0 + wc * 32 + n * 16 + (lane & 15);
        out[(size_t)row * 1024 + col] = acc[m][n][j] + bias[col];
      }
}

// ---------- causal flash attention: 32-row waves, 32x32x16 MFMA ----------
// r6-verified fragment algebra: block = 2 waves x 32 q-rows (one 64-row qt unit).
// ST = K@Q^T (col=lane&31=q): lane holds 32 P of ONE q-row (16 per key-half,
// partner lane+32 holds interleaved keys). Softmax local + xor32, T13 defer-max
// (lane-local rescale). P exchange: 4 shfl_xor(32)+selects per kstep. PV as
// O^T = V^T @ P. K via global_load_lds (pre-swizzled src); V reg-staged ->
// transposed swizzled LDS, double-buffered write-late.
__device__ __forceinline__ void attn_one(
    const u16* __restrict__ Qh, const u16* __restrict__ Kh, const u16* __restrict__ Vh,
    u16* __restrict__ Ob, int bb, int h, int qt,
    u16 (*Ks)[64 * 64], u16 (*Vt)[64 * 64]) {
  const int tid = threadIdx.x, lane = tid & 63, w = tid >> 6;   // w in 0..1
  const int half = lane >> 5, q31 = lane & 31;
  const int qrow = qt * 64 + w * 32 + q31;

  // Q fragment (B-operand): lane holds Q[qrow][ds*16 + 8*half + i]
  bf16x8 qf[4];
  #pragma unroll
  for (int ds = 0; ds < 4; ++ds)
    qf[ds] = *(const bf16x8*)(Qh + (size_t)qrow * 64 + ds * 16 + half * 8);

  f32x16 acc_o[2] = {};
  float m_run = -INFINITY, l_run = 0.f;
  const int nt = qt + 1;

  auto stageK = [&](int t, int buf) {    // 4 gload16 per thread
    #pragma unroll
    for (int it = 0; it < 4; ++it) {
      int c = it * 128 + tid;
      int row = c >> 3, b8 = c & 7;
      gload16(Kh + (size_t)(t * 64 + row) * 64 + ((b8 ^ (row & 7)) << 3),
              Ks[buf] + c * 8);
    }
  };
  auto loadV = [&](int t, u16x8 vreg[4]) {
    #pragma unroll
    for (int it = 0; it < 4; ++it) {
      int kloc = it * 16 + (tid >> 3);
      int d0 = (tid & 7) << 3;
      vreg[it] = *(const u16x8*)(Vh + (size_t)(t * 64 + kloc) * 64 + d0);
    }
  };
  auto writeV = [&](const u16x8 vreg[4], int buf) {
    #pragma unroll
    for (int it = 0; it < 4; ++it) {
      int kloc = it * 16 + (tid >> 3);
      int d0 = (tid & 7) << 3;
      #pragma unroll
      for (int i = 0; i < 8; ++i) {
        int d = d0 + i;
        int fv = (d + (d >> 3)) & 7;
        Vt[buf][d * 64 + (((kloc >> 3) ^ fv) << 3) + (kloc & 7)] = vreg[it][i];
      }
    }
  };

  // ---- prologue: tile 0 ----
  stageK(0, 0);
  {
    u16x8 v0[4];
    loadV(0, v0);
    writeV(v0, 0);
  }
  __syncthreads();

  for (int t = 0; t < nt; ++t) {
    const int cur = t & 1;
    const bool pre = (t + 1 < nt);
    u16x8 vreg[4];
    if (pre) { stageK(t + 1, cur ^ 1); loadV(t + 1, vreg); }

    // ---- ST = K @ Q^T : accs[c] = D[key = c*32 + klocal(r)][q = q31] ----
    f32x16 accs[2] = {};
    __builtin_amdgcn_s_setprio(1);
    #pragma unroll
    for (int c = 0; c < 2; ++c) {
      #pragma unroll
      for (int ds = 0; ds < 4; ++ds) {
        int row = c * 32 + q31;
        int bi = 2 * ds + half;
        bf16x8 kf = *(const bf16x8*)(Ks[cur] + row * 64 + ((bi ^ (row & 7)) << 3));
        accs[c] = MFMA32(kf, qf[ds], accs[c]);
      }
    }
    __builtin_amdgcn_s_setprio(0);

    // causal mask on diagonal tile (klocal(r) = (r&3) + 8*(r>>2) + 4*half)
    if (t == nt - 1) {
      #pragma unroll
      for (int c = 0; c < 2; ++c)
        #pragma unroll
        for (int r = 0; r < 16; ++r) {
          int kg = t * 64 + c * 32 + (r & 3) + 8 * (r >> 2) + 4 * half;
          if (kg > qrow) accs[c][r] = -INFINITY;
        }
    }

    // ---- online softmax (exp2), row split across lane/lane+32, T13 defer ----
    float mj = accs[0][0];
    #pragma unroll
    for (int c = 0; c < 2; ++c)
      #pragma unroll
      for (int r = 0; r < 16; ++r) mj = fmaxf(mj, accs[c][r]);
    mj = fmaxf(mj, __shfl_xor(mj, 32));
    if (!__all(mj - m_run <= 8.0f)) {
      float mn = fmaxf(m_run, mj);
      float sc = exp2f(m_run - mn);
      m_run = mn;
      l_run *= sc;
      acc_o[0] *= sc;          // lane-local: O^T col = q = this lane's row
      acc_o[1] *= sc;
    }
    float rs = 0.f;
    #pragma unroll
    for (int c = 0; c < 2; ++c)
      #pragma unroll
      for (int r = 0; r < 16; ++r) {
        float p = exp2f(accs[c][r] - m_run);
        accs[c][r] = p;
        rs += p;
      }
    rs += __shfl_xor(rs, 32);
    l_run += rs;

    // ---- pack P: Wp[c][m] = keys {klocal(2m), klocal(2m+1)} (+32c) ----
    unsigned Wp[2][8];
    #pragma unroll
    for (int c = 0; c < 2; ++c)
      #pragma unroll
      for (int m = 0; m < 8; ++m)
        asm("v_cvt_pk_bf16_f32 %0, %1, %2"
            : "=v"(Wp[c][m]) : "v"(accs[c][2 * m]), "v"(accs[c][2 * m + 1]));

    // ---- PV: O^T += V^T @ P, kstep k: B-frag = keys 16k + 8*half + 0..7 ----
    #pragma unroll
    for (int k = 0; k < 4; ++k) {
      const int c = k >> 1, g0 = 4 * (k & 1);
      unsigned x0 = (unsigned)__shfl_xor((int)Wp[c][g0 + 0], 32);
      unsigned x1 = (unsigned)__shfl_xor((int)Wp[c][g0 + 1], 32);
      unsigned x2 = (unsigned)__shfl_xor((int)Wp[c][g0 + 2], 32);
      unsigned x3 = (unsigned)__shfl_xor((int)Wp[c][g0 + 3], 32);
      unsigned pa0 = half ? x2 : Wp[c][g0 + 0];
      unsigned pa1 = half ? x3 : Wp[c][g0 + 1];
      unsigned pa2 = half ? Wp[c][g0 + 2] : x0;
      unsigned pa3 = half ? Wp[c][g0 + 3] : x1;
      bf16x8 pb = __builtin_bit_cast(bf16x8, (u32x4){pa0, pa1, pa2, pa3});
      __builtin_amdgcn_s_setprio(1);
      #pragma unroll
      for (int n = 0; n < 2; ++n) {
        int d = n * 32 + q31;
        int fv = (d + (d >> 3)) & 7;
        int bi = 2 * k + half;
        bf16x8 vfr = *(const bf16x8*)(Vt[cur] + d * 64 + ((bi ^ fv) << 3));
        acc_o[n] = MFMA32(vfr, pb, acc_o[n]);
      }
      __builtin_amdgcn_s_setprio(0);
    }

    if (pre) writeV(vreg, cur ^ 1);   // write-late after compute
    __syncthreads();
  }

  // ---- epilogue: O^T lane-local 1/l; write bf16 rows of [B*C, H] ----
  float invl = 1.0f / l_run;
  #pragma unroll
  for (int n = 0; n < 2; ++n)
    #pragma unroll
    for (int rq = 0; rq < 4; ++rq) {
      int dbase = n * 32 + 8 * rq + 4 * half;
      u16 o0 = f2bf(acc_o[n][4 * rq + 0] * invl);
      u16 o1 = f2bf(acc_o[n][4 * rq + 1] * invl);
      u16 o2 = f2bf(acc_o[n][4 * rq + 2] * invl);
      u16 o3 = f2bf(acc_o[n][4 * rq + 3] * invl);
      unsigned lo = (unsigned)o0 | ((unsigned)o1 << 16);
      unsigned hi = (unsigned)o2 | ((unsigned)o3 << 16);
      size_t idx = ((size_t)(bb * 2048 + qrow)) * 1024 + h * 64 + dbase;
      *(u32x2*)(Ob + idx) = (u32x2){lo, hi};
    }
}

// 1024 blocks x 128 threads; scrambled qt map: co-resident groups {b, b+256,
// b+512, b+768} (round-robin CU placement) get qts {2j, 2j+1, 31-2j, 30-2j}
// -> exactly 66 KV tiles per CU.
__global__ __launch_bounds__(128, 2) void attn_kernel(
    const u16* __restrict__ Qb, const u16* __restrict__ Kb, const u16* __restrict__ Vb,
    u16* __restrict__ Ob) {
  __shared__ __align__(16) u16 Ks[2][64 * 64];
  __shared__ __align__(16) u16 Vt[2][64 * 64];
  const int b = blockIdx.x;
  const int k = b >> 8, i = b & 255;
  const int bh = i >> 3, j = i & 7;
  const int qt = (k == 0) ? 2 * j : (k == 1) ? 2 * j + 1
               : (k == 2) ? 31 - 2 * j : 30 - 2 * j;
  const size_t base = (size_t)bh * 2048 * 64;
  attn_one(Qb + base, Kb + base, Vb + base, Ob, bh >> 4, bh & 15, qt, Ks, Vt);
}

// ---------- launch ----------
extern "C" void kernel_launch(void* const* d_in, const int* in_sizes, int n_in,
                              void* d_out, int out_size, void* d_ws, size_t ws_size,
                              hipStream_t stream) {
  const float* x    = (const float*)d_in[0];   // [2,2048,1024]
  const float* wqkv = (const float*)d_in[1];   // [3072,1024]
  const float* bqkv = (const float*)d_in[2];   // [3072]
  const float* wo   = (const float*)d_in[3];   // [1024,1024]
  const float* bo   = (const float*)d_in[4];   // [1024]
  float* out = (float*)d_out;                  // [4096,1024] fp32

  const size_t MB = 1u << 20;
  char* ws = (char*)d_ws;
  u16* x_bf  = (u16*)(ws);             // 8 MB
  u16* wq_bf = (u16*)(ws + 8 * MB);    // 6 MB
  u16* wo_bf = (u16*)(ws + 14 * MB);   // 2 MB
  u16* q_buf = (u16*)(ws + 16 * MB);   // 8 MB  [B,nh,C,64]
  u16* k_buf = (u16*)(ws + 24 * MB);   // 8 MB
  u16* v_buf = (u16*)(ws + 32 * MB);   // 8 MB
  u16* a_out = (u16*)(ws + 40 * MB);   // 8 MB  [4096,1024]

  cast_all_kernel<<<8192, 256, 0, stream>>>(x, wqkv, wo, x_bf, wq_bf, wo_bf);

  gemm_qkv_kernel<<<dim3(24, 32), 256, 0, stream>>>(x_bf, wq_bf, bqkv,
                                                    q_buf, k_buf, v_buf);
  attn_kernel<<<1024, 128, 0, stream>>>(q_buf, k_buf, v_buf, a_out);
  gemm_out_kernel<<<dim3(8, 64), 256, 0, stream>>>(a_out, wo_bf, bo, out);
}

// Round 14
// 151.059 us; speedup vs baseline: 1.0046x; 1.0046x over previous
//
#include <hip/hip_runtime.h>
#include <hip/hip_bf16.h>
#include <math.h>

typedef unsigned short u16;
typedef __attribute__((ext_vector_type(8))) __bf16 bf16x8;
typedef __attribute__((ext_vector_type(4))) float f32x4;
typedef __attribute__((ext_vector_type(8))) unsigned short u16x8;
typedef __attribute__((ext_vector_type(4))) unsigned int u32x4;

// ---------- helpers ----------
__device__ __forceinline__ u16 f2bf(float f) {
  union { float f; unsigned u; } x; x.f = f;
  unsigned r = x.u + 0x7fffu + ((x.u >> 16) & 1u);   // RNE
  return (u16)(r >> 16);
}

__device__ __forceinline__ void gload16(const u16* g, u16* l) {
  __builtin_amdgcn_global_load_lds(
      (const __attribute__((address_space(1))) void*)g,
      (__attribute__((address_space(3))) void*)l, 16, 0, 0);
}

#define MFMA16(a, b, c) __builtin_amdgcn_mfma_f32_16x16x32_bf16((a), (b), (c), 0, 0, 0)

// Q pre-scale: 1/sqrt(64) * log2(e)  (softmax done in exp2 domain)
#define QSCALE 0.18033688011112043f

// ---------- merged cast fp32 -> bf16 (x, Wqkv, Wo in one launch) ----------
__global__ __launch_bounds__(256) void cast_all_kernel(
    const float* __restrict__ x, const float* __restrict__ wqkv,
    const float* __restrict__ wo, u16* __restrict__ xb,
    u16* __restrict__ wqb, u16* __restrict__ wob) {
  int i = blockIdx.x * 256 + threadIdx.x;   // in float4 units
  const float* src; u16* dst;
  if (i < 1048576)      { src = x;    dst = xb;  }
  else if (i < 1835008) { src = wqkv; dst = wqb; i -= 1048576; }
  else                  { src = wo;   dst = wob; i -= 1835008; }
  f32x4 v = *(const f32x4*)(src + (size_t)i * 4);
  u16 o0 = f2bf(v[0]), o1 = f2bf(v[1]), o2 = f2bf(v[2]), o3 = f2bf(v[3]);
  unsigned lo = (unsigned)o0 | ((unsigned)o1 << 16);
  unsigned hi = (unsigned)o2 | ((unsigned)o3 << 16);
  ((unsigned*)dst)[(size_t)i * 2] = lo;
  ((unsigned*)dst)[(size_t)i * 2 + 1] = hi;
}

// ---------- shared 128x128 / BK=64 bf16 GEMM main loop (C = A * B^T) ----------
__device__ __forceinline__ void gemm_bt_128(
    const u16* __restrict__ A, const u16* __restrict__ B, int K, int m0, int n0,
    u16* As, u16* Bs, f32x4 acc[4][4]) {
  const int tid = threadIdx.x;
  const int lane = tid & 63;
  const int wr = tid >> 7;
  const int wc = (tid >> 6) & 1;
  for (int k0 = 0; k0 < K; k0 += 64) {
    #pragma unroll
    for (int it = 0; it < 4; ++it) {
      int c = it * 256 + tid;
      int row = c >> 3;
      int ko = (c & 7) << 3;
      gload16(A + (size_t)(m0 + row) * K + (k0 + ko), As + c * 8);
      gload16(B + (size_t)(n0 + row) * K + (k0 + ko), Bs + c * 8);
    }
    __syncthreads();
    #pragma unroll
    for (int kk = 0; kk < 2; ++kk) {
      bf16x8 a[4], b[4];
      #pragma unroll
      for (int m = 0; m < 4; ++m)
        a[m] = *(const bf16x8*)(As + ((wr * 64 + m * 16 + (lane & 15)) * 64 +
                                      kk * 32 + ((lane >> 4) << 3)));
      #pragma unroll
      for (int n = 0; n < 4; ++n)
        b[n] = *(const bf16x8*)(Bs + ((wc * 64 + n * 16 + (lane & 15)) * 64 +
                                      kk * 32 + ((lane >> 4) << 3)));
      #pragma unroll
      for (int m = 0; m < 4; ++m)
        #pragma unroll
        for (int n = 0; n < 4; ++n)
          acc[m][n] = MFMA16(a[m], b[n], acc[m][n]);
    }
    __syncthreads();
  }
}

// ---------- GEMM1: qkv = x @ Wqkv^T + b, scatter q/k/v to [B,nh,C,64] bf16 ----------
// 1D grid 768 with XCD-chunked swizzle (T1): XCD k processes tiles
// [k*96, (k+1)*96) contiguously -> A/B panel reuse stays in that XCD's L2.
__global__ __launch_bounds__(256) void gemm_qkv_kernel(
    const u16* __restrict__ X, const u16* __restrict__ W, const float* __restrict__ bias,
    u16* __restrict__ Qb, u16* __restrict__ Kb, u16* __restrict__ Vb) {
  __shared__ __align__(16) u16 S[17408];   // 2x 128x64 staging, reused as 128x136 C
  f32x4 acc[4][4];
  #pragma unroll
  for (int m = 0; m < 4; ++m)
    #pragma unroll
    for (int n = 0; n < 4; ++n) acc[m][n] = (f32x4){0.f, 0.f, 0.f, 0.f};
  const int b = blockIdx.x;                 // 0..767
  const int t = (b & 7) * 96 + (b >> 3);    // bijective: 768 = 8*96
  const int bx = t % 24, by = t / 24;
  const int m0 = by * 128;
  const int n0 = bx * 128;
  gemm_bt_128(X, W, 1024, m0, n0, S, S + 8192, acc);

  const int tid = threadIdx.x;
  const int lane = tid & 63;
  const int wr = tid >> 7, wc = (tid >> 6) & 1;
  const int which = n0 >> 10;                       // 0=Q 1=K 2=V (block-uniform)
  const float qs = (which == 0) ? QSCALE : 1.0f;
  u16* __restrict__ dst = (which == 0) ? Qb : (which == 1 ? Kb : Vb);

  // stage C-tile (bias + scale applied) into LDS
  #pragma unroll
  for (int m = 0; m < 4; ++m)
    #pragma unroll
    for (int n = 0; n < 4; ++n)
      #pragma unroll
      for (int j = 0; j < 4; ++j) {
        int row = wr * 64 + m * 16 + ((lane >> 4) << 2) + j;
        int col = wc * 64 + n * 16 + (lane & 15);
        float v = (acc[m][n][j] + bias[n0 + col]) * qs;
        S[row * 136 + col] = f2bf(v);
      }
  __syncthreads();

  // vectorized store: 2048 16B-chunks, 8 per thread
  #pragma unroll
  for (int i = 0; i < 8; ++i) {
    int c = i * 256 + tid;
    int row = c >> 4, ch = c & 15;
    u16x8 val = *(const u16x8*)(S + row * 136 + ch * 8);
    int grow = m0 + row;
    int bb = grow >> 11, q = grow & 2047;
    int gcol = n0 + ch * 8;
    int h = (gcol >> 6) & 15, d0 = gcol & 63;
    *(u16x8*)(dst + ((size_t)((bb * 16 + h) * 2048 + q)) * 64 + d0) = val;
  }
}

// ---------- GEMM2: out = attn @ Wo^T + b (fp32 out), 64x128 tile ----------
// 1D grid 512 with XCD-chunked swizzle: per-XCD working set A 1MB + B 2MB
// fits the 4MB per-XCD L2.
__global__ __launch_bounds__(256) void gemm_out_kernel(
    const u16* __restrict__ Ain, const u16* __restrict__ W, const float* __restrict__ bias,
    float* __restrict__ out) {
  __shared__ __align__(16) u16 As[64 * 64];
  __shared__ __align__(16) u16 Bs[128 * 64];
  const int tid = threadIdx.x;
  const int lane = tid & 63;
  const int wc = tid >> 6;                 // wave -> 32-col group
  const int b = blockIdx.x;                // 0..511
  const int t = (b & 7) * 64 + (b >> 3);   // bijective: 512 = 8*64
  const int m0 = (t >> 3) * 64;            // y = t/8 (64 M-tiles)
  const int n0 = (t & 7) * 128;            // x = t%8 (8 N-tiles)
  f32x4 acc[4][2] = {};
  for (int k0 = 0; k0 < 1024; k0 += 64) {
    #pragma unroll
    for (int it = 0; it < 2; ++it) {
      int c = it * 256 + tid;
      gload16(Ain + (size_t)(m0 + (c >> 3)) * 1024 + k0 + ((c & 7) << 3), As + c * 8);
    }
    #pragma unroll
    for (int it = 0; it < 4; ++it) {
      int c = it * 256 + tid;
      gload16(W + (size_t)(n0 + (c >> 3)) * 1024 + k0 + ((c & 7) << 3), Bs + c * 8);
    }
    __syncthreads();
    #pragma unroll
    for (int kk = 0; kk < 2; ++kk) {
      bf16x8 a[4], b2[2];
      #pragma unroll
      for (int m = 0; m < 4; ++m)
        a[m] = *(const bf16x8*)(As + ((m * 16 + (lane & 15)) * 64 +
                                      kk * 32 + ((lane >> 4) << 3)));
      #pragma unroll
      for (int n = 0; n < 2; ++n)
        b2[n] = *(const bf16x8*)(Bs + ((wc * 32 + n * 16 + (lane & 15)) * 64 +
                                       kk * 32 + ((lane >> 4) << 3)));
      #pragma unroll
      for (int m = 0; m < 4; ++m)
        #pragma unroll
        for (int n = 0; n < 2; ++n)
          acc[m][n] = MFMA16(a[m], b2[n], acc[m][n]);
    }
    __syncthreads();
  }
  #pragma unroll
  for (int m = 0; m < 4; ++m)
    #pragma unroll
    for (int n = 0; n < 2; ++n)
      #pragma unroll
      for (int j = 0; j < 4; ++j) {
        int row = m0 + m * 16 + ((lane >> 4) << 2) + j;
        int col = n0 + wc * 32 + n * 16 + (lane & 15);
        out[(size_t)row * 1024 + col] = acc[m][n][j] + bias[col];
      }
}

// ---------- causal flash attention: swapped-QK^T, in-register softmax & P ----------
// r12-verified body (71.5 us): 4 waves x 16 q-rows, T13 defer-max, exp2 domain.
__device__ __forceinline__ void attn_one(
    const u16* __restrict__ Qh, const u16* __restrict__ Kh, const u16* __restrict__ Vh,
    u16* __restrict__ Ob, int bb, int h, int qt,
    u16 (*Ks)[64 * 64], u16 (*Vt)[64 * 64]) {
  const int tid = threadIdx.x, lane = tid & 63, w = tid >> 6;
  const int g = lane >> 4, q15 = lane & 15;

  // Q fragment (B-operand): lane holds Q[qrow][kk*32 + 8g + i]
  bf16x8 qf[2];
  const int qrow = qt * 64 + w * 16 + q15;
  #pragma unroll
  for (int kk = 0; kk < 2; ++kk)
    qf[kk] = *(const bf16x8*)(Qh + (size_t)qrow * 64 + kk * 32 + g * 8);

  f32x4 acc_o[4];
  #pragma unroll
  for (int n = 0; n < 4; ++n) acc_o[n] = (f32x4){0.f, 0.f, 0.f, 0.f};
  float m_run = -INFINITY, l_run = 0.f;

  const int nt = qt + 1;

  auto stageK = [&](int t, int buf) {
    #pragma unroll
    for (int it = 0; it < 2; ++it) {
      int c = it * 256 + tid;
      int row = c >> 3, b8 = c & 7;
      gload16(Kh + (size_t)(t * 64 + row) * 64 + ((b8 ^ (row & 7)) << 3),
              Ks[buf] + c * 8);
    }
  };

  // ---- prologue: tile 0 ----
  stageK(0, 0);
  #pragma unroll
  for (int it = 0; it < 2; ++it) {
    int kloc = it * 32 + (tid >> 3);
    int d0 = (tid & 7) << 3;
    u16x8 v = *(const u16x8*)(Vh + (size_t)kloc * 64 + d0);
    #pragma unroll
    for (int i = 0; i < 8; ++i) {
      int d = d0 + i;
      int fv = (d + (d >> 3)) & 7;
      Vt[0][d * 64 + (((kloc >> 3) ^ fv) << 3) + (kloc & 7)] = v[i];
    }
  }
  __syncthreads();

  for (int t = 0; t < nt; ++t) {
    const int cur = t & 1;
    const bool pre = (t + 1 < nt);
    u16x8 vreg[2];
    if (pre) {
      stageK(t + 1, cur ^ 1);
      #pragma unroll
      for (int it = 0; it < 2; ++it) {
        int kloc = it * 32 + (tid >> 3);
        int d0 = (tid & 7) << 3;
        vreg[it] = *(const u16x8*)(Vh + (size_t)((t + 1) * 64 + kloc) * 64 + d0);
      }
    }

    // ---- ST = K @ Q^T : lane holds P[q=q15][key = 16cb + 4g + j] ----
    f32x4 accs[4];
    __builtin_amdgcn_s_setprio(1);
    #pragma unroll
    for (int cb = 0; cb < 4; ++cb) {
      accs[cb] = (f32x4){0.f, 0.f, 0.f, 0.f};
      #pragma unroll
      for (int kk = 0; kk < 2; ++kk) {
        int row = cb * 16 + q15;
        int kblk = kk * 4 + g;
        bf16x8 kf = *(const bf16x8*)(Ks[cur] + row * 64 + ((kblk ^ (row & 7)) << 3));
        accs[cb] = MFMA16(kf, qf[kk], accs[cb]);
      }
    }
    __builtin_amdgcn_s_setprio(0);
    // causal mask on diagonal tile
    if (t == nt - 1) {
      #pragma unroll
      for (int cb = 0; cb < 4; ++cb)
        #pragma unroll
        for (int j = 0; j < 4; ++j) {
          int kg = t * 64 + cb * 16 + 4 * g + j;
          if (kg > qrow) accs[cb][j] = -INFINITY;
        }
    }

    // ---- online softmax (exp2 domain), lane-local q-row, T13 defer-max ----
    float mj = accs[0][0];
    #pragma unroll
    for (int cb = 0; cb < 4; ++cb)
      #pragma unroll
      for (int j = 0; j < 4; ++j) mj = fmaxf(mj, accs[cb][j]);
    mj = fmaxf(mj, __shfl_xor(mj, 16));
    mj = fmaxf(mj, __shfl_xor(mj, 32));
    if (!__all(mj - m_run <= 8.0f)) {
      float mn = fmaxf(m_run, mj);
      float sc = exp2f(m_run - mn);
      m_run = mn;
      l_run *= sc;
      float scj[4];
      #pragma unroll
      for (int j = 0; j < 4; ++j) scj[j] = __shfl(sc, 4 * g + j);
      #pragma unroll
      for (int n = 0; n < 4; ++n)
        #pragma unroll
        for (int j = 0; j < 4; ++j) acc_o[n][j] *= scj[j];
    }
    float rs = 0.f;
    #pragma unroll
    for (int cb = 0; cb < 4; ++cb)
      #pragma unroll
      for (int j = 0; j < 4; ++j) {
        float p = exp2f(accs[cb][j] - m_run);
        accs[cb][j] = p;
        rs += p;
      }
    rs += __shfl_xor(rs, 16);
    rs += __shfl_xor(rs, 32);
    l_run += rs;

    // ---- pack P to bf16 pairs: Wp[cb][hh] = keys (16cb+4g+2hh, +1) ----
    unsigned Wp[4][2];
    #pragma unroll
    for (int cb = 0; cb < 4; ++cb)
      #pragma unroll
      for (int hh = 0; hh < 2; ++hh)
        asm("v_cvt_pk_bf16_f32 %0, %1, %2"
            : "=v"(Wp[cb][hh]) : "v"(accs[cb][2 * hh]), "v"(accs[cb][2 * hh + 1]));

    // ---- exchange into PV A-fragments: lane needs keys kk*32+8g..+7 ----
    unsigned aw[2][4];
    #pragma unroll
    for (int kk = 0; kk < 2; ++kk)
      #pragma unroll
      for (int iw = 0; iw < 4; ++iw) {
        int srcLane = q15 + ((((g & 1) << 1) + (iw >> 1)) << 4);
        unsigned c0 = __shfl(Wp[2 * kk + 0][iw & 1], srcLane);
        unsigned c1 = __shfl(Wp[2 * kk + 1][iw & 1], srcLane);
        aw[kk][iw] = (g >> 1) ? c1 : c0;
      }
    bf16x8 pa0 = __builtin_bit_cast(bf16x8, (u32x4){aw[0][0], aw[0][1], aw[0][2], aw[0][3]});
    bf16x8 pa1 = __builtin_bit_cast(bf16x8, (u32x4){aw[1][0], aw[1][1], aw[1][2], aw[1][3]});

    // ---- O += P @ V  (V via swizzled ds_read_b128) ----
    __builtin_amdgcn_s_setprio(1);
    #pragma unroll
    for (int n = 0; n < 4; ++n) {
      #pragma unroll
      for (int kk = 0; kk < 2; ++kk) {
        int cblk = kk * 4 + g;
        int d = n * 16 + q15;
        int fv = (d + (d >> 3)) & 7;
        bf16x8 vb = *(const bf16x8*)(Vt[cur] + d * 64 + ((cblk ^ fv) << 3));
        acc_o[n] = MFMA16(kk ? pa1 : pa0, vb, acc_o[n]);
      }
    }
    __builtin_amdgcn_s_setprio(0);

    if (pre) {
      // write-late: V regs -> LDS (swizzled) after compute
      #pragma unroll
      for (int it = 0; it < 2; ++it) {
        int kloc = it * 32 + (tid >> 3);
        int d0 = (tid & 7) << 3;
        #pragma unroll
        for (int i = 0; i < 8; ++i) {
          int d = d0 + i;
          int fv = (d + (d >> 3)) & 7;
          Vt[cur ^ 1][d * 64 + (((kloc >> 3) ^ fv) << 3) + (kloc & 7)] = vreg[it][i];
        }
      }
    }
    __syncthreads();
  }

  // ---- epilogue: O /= l, write bf16 to [B*C, H] ----
  float invl = 1.0f / l_run;
  float invj[4];
  #pragma unroll
  for (int j = 0; j < 4; ++j) invj[j] = __shfl(invl, 4 * g + j);
  #pragma unroll
  for (int n = 0; n < 4; ++n)
    #pragma unroll
    for (int j = 0; j < 4; ++j) {
      int qg = qt * 64 + w * 16 + 4 * g + j;
      Ob[((size_t)(bb * 2048 + qg)) * 1024 + h * 64 + n * 16 + q15] =
          f2bf(acc_o[n][j] * invj[j]);
    }
}

// grid = 32 heads x 16 balanced pairs; block handles q-tiles (31-p, p): 33 KV tiles.
__global__ __launch_bounds__(256, 4) void attn_kernel(
    const u16* __restrict__ Qb, const u16* __restrict__ Kb, const u16* __restrict__ Vb,
    u16* __restrict__ Ob) {
  __shared__ __align__(16) u16 Ks[2][64 * 64];
  __shared__ __align__(16) u16 Vt[2][64 * 64];
  const int blk = blockIdx.x;
  const int p = blk & 15;
  const int bh = blk >> 4;             // 0..31 (b*16+h)
  const size_t base = (size_t)bh * 2048 * 64;
  const int bb = bh >> 4, h = bh & 15;
  attn_one(Qb + base, Kb + base, Vb + base, Ob, bb, h, 31 - p, Ks, Vt);
  attn_one(Qb + base, Kb + base, Vb + base, Ob, bb, h, p, Ks, Vt);
}

// ---------- launch ----------
extern "C" void kernel_launch(void* const* d_in, const int* in_sizes, int n_in,
                              void* d_out, int out_size, void* d_ws, size_t ws_size,
                              hipStream_t stream) {
  const float* x    = (const float*)d_in[0];   // [2,2048,1024]
  const float* wqkv = (const float*)d_in[1];   // [3072,1024]
  const float* bqkv = (const float*)d_in[2];   // [3072]
  const float* wo   = (const float*)d_in[3];   // [1024,1024]
  const float* bo   = (const float*)d_in[4];   // [1024]
  float* out = (float*)d_out;                  // [4096,1024] fp32

  const size_t MB = 1u << 20;
  char* ws = (char*)d_ws;
  u16* x_bf  = (u16*)(ws);             // 8 MB
  u16* wq_bf = (u16*)(ws + 8 * MB);    // 6 MB
  u16* wo_bf = (u16*)(ws + 14 * MB);   // 2 MB
  u16* q_buf = (u16*)(ws + 16 * MB);   // 8 MB  [B,nh,C,64]
  u16* k_buf = (u16*)(ws + 24 * MB);   // 8 MB
  u16* v_buf = (u16*)(ws + 32 * MB);   // 8 MB
  u16* a_out = (u16*)(ws + 40 * MB);   // 8 MB  [4096,1024]

  cast_all_kernel<<<8192, 256, 0, stream>>>(x, wqkv, wo, x_bf, wq_bf, wo_bf);

  gemm_qkv_kernel<<<768, 256, 0, stream>>>(x_bf, wq_bf, bqkv,
                                           q_buf, k_buf, v_buf);
  attn_kernel<<<512, 256, 0, stream>>>(q_buf, k_buf, v_buf, a_out);
  gemm_out_kernel<<<512, 256, 0, stream>>>(a_out, wo_bf, bo, out);
}

// Round 15
// 144.664 us; speedup vs baseline: 1.0490x; 1.0442x over previous
//
#include <hip/hip_runtime.h>
#include <hip/hip_bf16.h>
#include <math.h>

typedef unsigned short u16;
typedef __attribute__((ext_vector_type(8))) __bf16 bf16x8;
typedef __attribute__((ext_vector_type(4))) float f32x4;
typedef __attribute__((ext_vector_type(8))) unsigned short u16x8;
typedef __attribute__((ext_vector_type(4))) unsigned int u32x4;

// ---------- helpers ----------
__device__ __forceinline__ u16 f2bf(float f) {
  union { float f; unsigned u; } x; x.f = f;
  unsigned r = x.u + 0x7fffu + ((x.u >> 16) & 1u);   // RNE
  return (u16)(r >> 16);
}

__device__ __forceinline__ void gload16(const u16* g, u16* l) {
  __builtin_amdgcn_global_load_lds(
      (const __attribute__((address_space(1))) void*)g,
      (__attribute__((address_space(3))) void*)l, 16, 0, 0);
}

#define MFMA16(a, b, c) __builtin_amdgcn_mfma_f32_16x16x32_bf16((a), (b), (c), 0, 0, 0)

// Q pre-scale: 1/sqrt(64) * log2(e)  (softmax done in exp2 domain)
#define QSCALE 0.18033688011112043f

// ---------- merged cast fp32 -> bf16 (x, Wqkv, Wo in one launch) ----------
__global__ __launch_bounds__(256) void cast_all_kernel(
    const float* __restrict__ x, const float* __restrict__ wqkv,
    const float* __restrict__ wo, u16* __restrict__ xb,
    u16* __restrict__ wqb, u16* __restrict__ wob) {
  int i = blockIdx.x * 256 + threadIdx.x;   // in float4 units
  const float* src; u16* dst;
  if (i < 1048576)      { src = x;    dst = xb;  }
  else if (i < 1835008) { src = wqkv; dst = wqb; i -= 1048576; }
  else                  { src = wo;   dst = wob; i -= 1835008; }
  f32x4 v = *(const f32x4*)(src + (size_t)i * 4);
  u16 o0 = f2bf(v[0]), o1 = f2bf(v[1]), o2 = f2bf(v[2]), o3 = f2bf(v[3]);
  unsigned lo = (unsigned)o0 | ((unsigned)o1 << 16);
  unsigned hi = (unsigned)o2 | ((unsigned)o3 << 16);
  ((unsigned*)dst)[(size_t)i * 2] = lo;
  ((unsigned*)dst)[(size_t)i * 2 + 1] = hi;
}

// ---------- GEMM1: 256x256 tile, BK=64, 8 waves, 8-phase counted-vmcnt ----------
// qkv = x @ Wqkv^T + b, scattered to q/k/v [B,nh,C,64] bf16.
// Phase q of K-tile kt: C-quadrant m in {2q,2q+1} x 4n x K=64 (16 MFMA).
// Staging: group kt stages A(kt+1) at q0,q1 (idle dbuf) and B(kt+2) at q2,q3
// (B slots of kt are dead after q0 - B-frags held in regs). Boundary wait
// vmcnt(4) (2 half-tiles in flight); raw s_barrier; st_16x32 swizzle as
// lane-local k-group XOR applied on BOTH gload source and ds_read (rule 21).
__global__ __launch_bounds__(512, 2) void gemm_qkv_kernel(
    const u16* __restrict__ X, const u16* __restrict__ W, const float* __restrict__ bias,
    u16* __restrict__ Qb, u16* __restrict__ Kb, u16* __restrict__ Vb) {
  __shared__ __align__(16) u16 As[2][2][128 * 64];   // [dbuf][mhalf][row*64+k]
  __shared__ __align__(16) u16 Bs[2][2][128 * 64];   // [dbuf][nhalf][row*64+k]
  const int tid = threadIdx.x;
  const int lane = tid & 63;
  const int wid = tid >> 6;
  const int wm = wid >> 2, wn = wid & 3;          // 2M x 4N wave grid
  const int g = lane >> 4, q15 = lane & 15;
  const int m0b = blockIdx.y * 256;
  const int n0b = blockIdx.x * 256;
  const int sA = 2 * ((q15 >> 2) & 1);            // read-side k-group XOR

  auto stageA = [&](int kt, int h) {
    #pragma unroll
    for (int it = 0; it < 2; ++it) {
      int c = it * 512 + tid;
      int row = c >> 3, kg = c & 7;
      int kgs = kg ^ (2 * ((row >> 2) & 1));      // pre-swizzled SOURCE
      gload16(X + (size_t)(m0b + h * 128 + row) * 1024 + kt * 64 + kgs * 8,
              &As[kt & 1][h][c * 8]);             // linear LDS dest
    }
  };
  auto stageB = [&](int kt, int h) {
    #pragma unroll
    for (int it = 0; it < 2; ++it) {
      int c = it * 512 + tid;
      int row = c >> 3, kg = c & 7;
      int kgs = kg ^ (2 * ((row >> 2) & 1));
      gload16(W + (size_t)(n0b + h * 128 + row) * 1024 + kt * 64 + kgs * 8,
              &Bs[kt & 1][h][c * 8]);
    }
  };

  f32x4 acc[8][4] = {};

  // ---- prologue: A(0), B(0), B(1); wait leaves B(1) in flight ----
  stageA(0, 0); stageA(0, 1);
  stageB(0, 0); stageB(0, 1);
  stageB(1, 0); stageB(1, 1);
  asm volatile("s_waitcnt vmcnt(4)" ::: "memory");
  __builtin_amdgcn_s_barrier();

  for (int kt = 0; kt < 16; ++kt) {
    const int d = kt & 1;
    const u16* Ah = As[d][wm];
    const u16* Bh = Bs[d][wn >> 1];
    const int rB0 = (wn & 1) * 64;
    bf16x8 bfr[4][2];
    #pragma unroll
    for (int q = 0; q < 4; ++q) {
      bf16x8 afr[2][2];
      if (q == 0) {                               // 8 B-frags, held across phases
        #pragma unroll
        for (int n = 0; n < 4; ++n)
          #pragma unroll
          for (int kk = 0; kk < 2; ++kk) {
            int row = rB0 + n * 16 + q15;
            int kg = (kk * 4 + g) ^ sA;
            bfr[n][kk] = *(const bf16x8*)(Bh + row * 64 + kg * 8);
          }
      }
      #pragma unroll
      for (int p = 0; p < 2; ++p)
        #pragma unroll
        for (int kk = 0; kk < 2; ++kk) {
          int row = (2 * q + p) * 16 + q15;
          int kg = (kk * 4 + g) ^ sA;
          afr[p][kk] = *(const bf16x8*)(Ah + row * 64 + kg * 8);
        }
      // stage one half-tile per phase
      if (q == 0)      { if (kt + 1 < 16) stageA(kt + 1, 0); }
      else if (q == 1) { if (kt + 1 < 16) stageA(kt + 1, 1); }
      else if (q == 2) { if (kt + 2 < 16) stageB(kt + 2, 0); }
      else             { if (kt + 2 < 16) stageB(kt + 2, 1); }
      __builtin_amdgcn_s_barrier();
      asm volatile("s_waitcnt lgkmcnt(0)" ::: "memory");
      __builtin_amdgcn_sched_barrier(0);
      __builtin_amdgcn_s_setprio(1);
      #pragma unroll
      for (int kk = 0; kk < 2; ++kk)
        #pragma unroll
        for (int p = 0; p < 2; ++p)
          #pragma unroll
          for (int n = 0; n < 4; ++n)
            acc[2 * q + p][n] = MFMA16(afr[p][kk], bfr[n][kk], acc[2 * q + p][n]);
      __builtin_amdgcn_s_setprio(0);
      if (q == 3) {                               // counted boundary wait
        if (kt < 14)       asm volatile("s_waitcnt vmcnt(4)" ::: "memory");
        else if (kt == 14) asm volatile("s_waitcnt vmcnt(0)" ::: "memory");
      }
      __builtin_amdgcn_s_barrier();
    }
  }

  // ---- epilogue: bias + Q-scale, scatter to per-head layouts ----
  const int which = n0b >> 10;                    // 0=Q 1=K 2=V (block-uniform)
  const float qs = (which == 0) ? QSCALE : 1.0f;
  u16* __restrict__ dst = (which == 0) ? Qb : (which == 1 ? Kb : Vb);
  #pragma unroll
  for (int n = 0; n < 4; ++n) {
    int gcol = n0b + wn * 64 + n * 16 + q15;
    float bz = bias[gcol];
    int h = (gcol >> 6) & 15, d0 = gcol & 63;
    #pragma unroll
    for (int m = 0; m < 8; ++m)
      #pragma unroll
      for (int j = 0; j < 4; ++j) {
        int grow = m0b + wm * 128 + m * 16 + g * 4 + j;
        int bb = grow >> 11, qq = grow & 2047;
        dst[((size_t)((bb * 16 + h) * 2048 + qq)) * 64 + d0] =
            f2bf((acc[m][n][j] + bz) * qs);
      }
  }
}

// ---------- GEMM2: out = attn @ Wo^T + b (fp32 out), 64x128 tile ----------
__global__ __launch_bounds__(256) void gemm_out_kernel(
    const u16* __restrict__ Ain, const u16* __restrict__ W, const float* __restrict__ bias,
    float* __restrict__ out) {
  __shared__ __align__(16) u16 As[64 * 64];
  __shared__ __align__(16) u16 Bs[128 * 64];
  const int tid = threadIdx.x;
  const int lane = tid & 63;
  const int wc = tid >> 6;                 // wave -> 32-col group
  const int m0 = blockIdx.y * 64;
  const int n0 = blockIdx.x * 128;
  f32x4 acc[4][2] = {};
  for (int k0 = 0; k0 < 1024; k0 += 64) {
    #pragma unroll
    for (int it = 0; it < 2; ++it) {
      int c = it * 256 + tid;
      gload16(Ain + (size_t)(m0 + (c >> 3)) * 1024 + k0 + ((c & 7) << 3), As + c * 8);
    }
    #pragma unroll
    for (int it = 0; it < 4; ++it) {
      int c = it * 256 + tid;
      gload16(W + (size_t)(n0 + (c >> 3)) * 1024 + k0 + ((c & 7) << 3), Bs + c * 8);
    }
    __syncthreads();
    #pragma unroll
    for (int kk = 0; kk < 2; ++kk) {
      bf16x8 a[4], b[2];
      #pragma unroll
      for (int m = 0; m < 4; ++m)
        a[m] = *(const bf16x8*)(As + ((m * 16 + (lane & 15)) * 64 +
                                      kk * 32 + ((lane >> 4) << 3)));
      #pragma unroll
      for (int n = 0; n < 2; ++n)
        b[n] = *(const bf16x8*)(Bs + ((wc * 32 + n * 16 + (lane & 15)) * 64 +
                                      kk * 32 + ((lane >> 4) << 3)));
      #pragma unroll
      for (int m = 0; m < 4; ++m)
        #pragma unroll
        for (int n = 0; n < 2; ++n)
          acc[m][n] = MFMA16(a[m], b[n], acc[m][n]);
    }
    __syncthreads();
  }
  #pragma unroll
  for (int m = 0; m < 4; ++m)
    #pragma unroll
    for (int n = 0; n < 2; ++n)
      #pragma unroll
      for (int j = 0; j < 4; ++j) {
        int row = m0 + m * 16 + ((lane >> 4) << 2) + j;
        int col = n0 + wc * 32 + n * 16 + (lane & 15);
        out[(size_t)row * 1024 + col] = acc[m][n][j] + bias[col];
      }
}

// ---------- causal flash attention: swapped-QK^T, in-register softmax & P ----------
// r12-verified body (71.5 us): 4 waves x 16 q-rows, T13 defer-max, exp2 domain.
__device__ __forceinline__ void attn_one(
    const u16* __restrict__ Qh, const u16* __restrict__ Kh, const u16* __restrict__ Vh,
    u16* __restrict__ Ob, int bb, int h, int qt,
    u16 (*Ks)[64 * 64], u16 (*Vt)[64 * 64]) {
  const int tid = threadIdx.x, lane = tid & 63, w = tid >> 6;
  const int g = lane >> 4, q15 = lane & 15;

  // Q fragment (B-operand): lane holds Q[qrow][kk*32 + 8g + i]
  bf16x8 qf[2];
  const int qrow = qt * 64 + w * 16 + q15;
  #pragma unroll
  for (int kk = 0; kk < 2; ++kk)
    qf[kk] = *(const bf16x8*)(Qh + (size_t)qrow * 64 + kk * 32 + g * 8);

  f32x4 acc_o[4];
  #pragma unroll
  for (int n = 0; n < 4; ++n) acc_o[n] = (f32x4){0.f, 0.f, 0.f, 0.f};
  float m_run = -INFINITY, l_run = 0.f;

  const int nt = qt + 1;

  auto stageK = [&](int t, int buf) {
    #pragma unroll
    for (int it = 0; it < 2; ++it) {
      int c = it * 256 + tid;
      int row = c >> 3, b8 = c & 7;
      gload16(Kh + (size_t)(t * 64 + row) * 64 + ((b8 ^ (row & 7)) << 3),
              Ks[buf] + c * 8);
    }
  };

  // ---- prologue: tile 0 ----
  stageK(0, 0);
  #pragma unroll
  for (int it = 0; it < 2; ++it) {
    int kloc = it * 32 + (tid >> 3);
    int d0 = (tid & 7) << 3;
    u16x8 v = *(const u16x8*)(Vh + (size_t)kloc * 64 + d0);
    #pragma unroll
    for (int i = 0; i < 8; ++i) {
      int d = d0 + i;
      int fv = (d + (d >> 3)) & 7;
      Vt[0][d * 64 + (((kloc >> 3) ^ fv) << 3) + (kloc & 7)] = v[i];
    }
  }
  __syncthreads();

  for (int t = 0; t < nt; ++t) {
    const int cur = t & 1;
    const bool pre = (t + 1 < nt);
    u16x8 vreg[2];
    if (pre) {
      stageK(t + 1, cur ^ 1);
      #pragma unroll
      for (int it = 0; it < 2; ++it) {
        int kloc = it * 32 + (tid >> 3);
        int d0 = (tid & 7) << 3;
        vreg[it] = *(const u16x8*)(Vh + (size_t)((t + 1) * 64 + kloc) * 64 + d0);
      }
    }

    // ---- ST = K @ Q^T : lane holds P[q=q15][key = 16cb + 4g + j] ----
    f32x4 accs[4];
    __builtin_amdgcn_s_setprio(1);
    #pragma unroll
    for (int cb = 0; cb < 4; ++cb) {
      accs[cb] = (f32x4){0.f, 0.f, 0.f, 0.f};
      #pragma unroll
      for (int kk = 0; kk < 2; ++kk) {
        int row = cb * 16 + q15;
        int kblk = kk * 4 + g;
        bf16x8 kf = *(const bf16x8*)(Ks[cur] + row * 64 + ((kblk ^ (row & 7)) << 3));
        accs[cb] = MFMA16(kf, qf[kk], accs[cb]);
      }
    }
    __builtin_amdgcn_s_setprio(0);
    // causal mask on diagonal tile
    if (t == nt - 1) {
      #pragma unroll
      for (int cb = 0; cb < 4; ++cb)
        #pragma unroll
        for (int j = 0; j < 4; ++j) {
          int kg = t * 64 + cb * 16 + 4 * g + j;
          if (kg > qrow) accs[cb][j] = -INFINITY;
        }
    }

    // ---- online softmax (exp2 domain), lane-local q-row, T13 defer-max ----
    float mj = accs[0][0];
    #pragma unroll
    for (int cb = 0; cb < 4; ++cb)
      #pragma unroll
      for (int j = 0; j < 4; ++j) mj = fmaxf(mj, accs[cb][j]);
    mj = fmaxf(mj, __shfl_xor(mj, 16));
    mj = fmaxf(mj, __shfl_xor(mj, 32));
    if (!__all(mj - m_run <= 8.0f)) {
      float mn = fmaxf(m_run, mj);
      float sc = exp2f(m_run - mn);
      m_run = mn;
      l_run *= sc;
      float scj[4];
      #pragma unroll
      for (int j = 0; j < 4; ++j) scj[j] = __shfl(sc, 4 * g + j);
      #pragma unroll
      for (int n = 0; n < 4; ++n)
        #pragma unroll
        for (int j = 0; j < 4; ++j) acc_o[n][j] *= scj[j];
    }
    float rs = 0.f;
    #pragma unroll
    for (int cb = 0; cb < 4; ++cb)
      #pragma unroll
      for (int j = 0; j < 4; ++j) {
        float p = exp2f(accs[cb][j] - m_run);
        accs[cb][j] = p;
        rs += p;
      }
    rs += __shfl_xor(rs, 16);
    rs += __shfl_xor(rs, 32);
    l_run += rs;

    // ---- pack P to bf16 pairs: Wp[cb][hh] = keys (16cb+4g+2hh, +1) ----
    unsigned Wp[4][2];
    #pragma unroll
    for (int cb = 0; cb < 4; ++cb)
      #pragma unroll
      for (int hh = 0; hh < 2; ++hh)
        asm("v_cvt_pk_bf16_f32 %0, %1, %2"
            : "=v"(Wp[cb][hh]) : "v"(accs[cb][2 * hh]), "v"(accs[cb][2 * hh + 1]));

    // ---- exchange into PV A-fragments: lane needs keys kk*32+8g..+7 ----
    unsigned aw[2][4];
    #pragma unroll
    for (int kk = 0; kk < 2; ++kk)
      #pragma unroll
      for (int iw = 0; iw < 4; ++iw) {
        int srcLane = q15 + ((((g & 1) << 1) + (iw >> 1)) << 4);
        unsigned c0 = __shfl(Wp[2 * kk + 0][iw & 1], srcLane);
        unsigned c1 = __shfl(Wp[2 * kk + 1][iw & 1], srcLane);
        aw[kk][iw] = (g >> 1) ? c1 : c0;
      }
    bf16x8 pa0 = __builtin_bit_cast(bf16x8, (u32x4){aw[0][0], aw[0][1], aw[0][2], aw[0][3]});
    bf16x8 pa1 = __builtin_bit_cast(bf16x8, (u32x4){aw[1][0], aw[1][1], aw[1][2], aw[1][3]});

    // ---- O += P @ V  (V via swizzled ds_read_b128) ----
    __builtin_amdgcn_s_setprio(1);
    #pragma unroll
    for (int n = 0; n < 4; ++n) {
      #pragma unroll
      for (int kk = 0; kk < 2; ++kk) {
        int cblk = kk * 4 + g;
        int d = n * 16 + q15;
        int fv = (d + (d >> 3)) & 7;
        bf16x8 vb = *(const bf16x8*)(Vt[cur] + d * 64 + ((cblk ^ fv) << 3));
        acc_o[n] = MFMA16(kk ? pa1 : pa0, vb, acc_o[n]);
      }
    }
    __builtin_amdgcn_s_setprio(0);

    if (pre) {
      // write-late: V regs -> LDS (swizzled) after compute
      #pragma unroll
      for (int it = 0; it < 2; ++it) {
        int kloc = it * 32 + (tid >> 3);
        int d0 = (tid & 7) << 3;
        #pragma unroll
        for (int i = 0; i < 8; ++i) {
          int d = d0 + i;
          int fv = (d + (d >> 3)) & 7;
          Vt[cur ^ 1][d * 64 + (((kloc >> 3) ^ fv) << 3) + (kloc & 7)] = vreg[it][i];
        }
      }
    }
    __syncthreads();
  }

  // ---- epilogue: O /= l, write bf16 to [B*C, H] ----
  float invl = 1.0f / l_run;
  float invj[4];
  #pragma unroll
  for (int j = 0; j < 4; ++j) invj[j] = __shfl(invl, 4 * g + j);
  #pragma unroll
  for (int n = 0; n < 4; ++n)
    #pragma unroll
    for (int j = 0; j < 4; ++j) {
      int qg = qt * 64 + w * 16 + 4 * g + j;
      Ob[((size_t)(bb * 2048 + qg)) * 1024 + h * 64 + n * 16 + q15] =
          f2bf(acc_o[n][j] * invj[j]);
    }
}

// grid = 32 heads x 16 balanced pairs; block handles q-tiles (31-p, p): 33 KV tiles.
__global__ __launch_bounds__(256, 4) void attn_kernel(
    const u16* __restrict__ Qb, const u16* __restrict__ Kb, const u16* __restrict__ Vb,
    u16* __restrict__ Ob) {
  __shared__ __align__(16) u16 Ks[2][64 * 64];
  __shared__ __align__(16) u16 Vt[2][64 * 64];
  const int blk = blockIdx.x;
  const int p = blk & 15;
  const int bh = blk >> 4;             // 0..31 (b*16+h)
  const size_t base = (size_t)bh * 2048 * 64;
  const int bb = bh >> 4, h = bh & 15;
  attn_one(Qb + base, Kb + base, Vb + base, Ob, bb, h, 31 - p, Ks, Vt);
  attn_one(Qb + base, Kb + base, Vb + base, Ob, bb, h, p, Ks, Vt);
}

// ---------- launch ----------
extern "C" void kernel_launch(void* const* d_in, const int* in_sizes, int n_in,
                              void* d_out, int out_size, void* d_ws, size_t ws_size,
                              hipStream_t stream) {
  const float* x    = (const float*)d_in[0];   // [2,2048,1024]
  const float* wqkv = (const float*)d_in[1];   // [3072,1024]
  const float* bqkv = (const float*)d_in[2];   // [3072]
  const float* wo   = (const float*)d_in[3];   // [1024,1024]
  const float* bo   = (const float*)d_in[4];   // [1024]
  float* out = (float*)d_out;                  // [4096,1024] fp32

  const size_t MB = 1u << 20;
  char* ws = (char*)d_ws;
  u16* x_bf  = (u16*)(ws);             // 8 MB
  u16* wq_bf = (u16*)(ws + 8 * MB);    // 6 MB
  u16* wo_bf = (u16*)(ws + 14 * MB);   // 2 MB
  u16* q_buf = (u16*)(ws + 16 * MB);   // 8 MB  [B,nh,C,64]
  u16* k_buf = (u16*)(ws + 24 * MB);   // 8 MB
  u16* v_buf = (u16*)(ws + 32 * MB);   // 8 MB
  u16* a_out = (u16*)(ws + 40 * MB);   // 8 MB  [4096,1024]

  cast_all_kernel<<<8192, 256, 0, stream>>>(x, wqkv, wo, x_bf, wq_bf, wo_bf);

  gemm_qkv_kernel<<<dim3(12, 16), 512, 0, stream>>>(x_bf, wq_bf, bqkv,
                                                    q_buf, k_buf, v_buf);
  attn_kernel<<<512, 256, 0, stream>>>(q_buf, k_buf, v_buf, a_out);
  gemm_out_kernel<<<dim3(8, 64), 256, 0, stream>>>(a_out, wo_bf, bo, out);
}

// Round 17
// 134.702 us; speedup vs baseline: 1.1266x; 1.0740x over previous
//
#include <hip/hip_runtime.h>
#include <hip/hip_bf16.h>
#include <math.h>

typedef unsigned short u16;
typedef __attribute__((ext_vector_type(8))) __bf16 bf16x8;
typedef __attribute__((ext_vector_type(4))) float f32x4;
typedef __attribute__((ext_vector_type(8))) unsigned short u16x8;
typedef __attribute__((ext_vector_type(4))) unsigned int u32x4;

// ---------- helpers ----------
__device__ __forceinline__ u16 f2bf(float f) {
  union { float f; unsigned u; } x; x.f = f;
  unsigned r = x.u + 0x7fffu + ((x.u >> 16) & 1u);   // RNE
  return (u16)(r >> 16);
}

__device__ __forceinline__ void gload16(const u16* g, u16* l) {
  __builtin_amdgcn_global_load_lds(
      (const __attribute__((address_space(1))) void*)g,
      (__attribute__((address_space(3))) void*)l, 16, 0, 0);
}

#define MFMA16(a, b, c) __builtin_amdgcn_mfma_f32_16x16x32_bf16((a), (b), (c), 0, 0, 0)

// Q pre-scale: 1/sqrt(64) * log2(e)  (softmax done in exp2 domain)
#define QSCALE 0.18033688011112043f

// ---------- merged cast fp32 -> bf16 (x, Wqkv, Wo in one launch) ----------
__global__ __launch_bounds__(256) void cast_all_kernel(
    const float* __restrict__ x, const float* __restrict__ wqkv,
    const float* __restrict__ wo, u16* __restrict__ xb,
    u16* __restrict__ wqb, u16* __restrict__ wob) {
  int i = blockIdx.x * 256 + threadIdx.x;   // in float4 units
  const float* src; u16* dst;
  if (i < 1048576)      { src = x;    dst = xb;  }
  else if (i < 1835008) { src = wqkv; dst = wqb; i -= 1048576; }
  else                  { src = wo;   dst = wob; i -= 1835008; }
  f32x4 v = *(const f32x4*)(src + (size_t)i * 4);
  u16 o0 = f2bf(v[0]), o1 = f2bf(v[1]), o2 = f2bf(v[2]), o3 = f2bf(v[3]);
  unsigned lo = (unsigned)o0 | ((unsigned)o1 << 16);
  unsigned hi = (unsigned)o2 | ((unsigned)o3 << 16);
  ((unsigned*)dst)[(size_t)i * 2] = lo;
  ((unsigned*)dst)[(size_t)i * 2 + 1] = hi;
}

// ---------- GEMM1: 256x256 tile, BK=64, 8 waves, 8-phase counted-vmcnt ----------
// Q,K written row-major per head [q][d]; V written per head per key-tile as
// contiguous [d=64][key=64] subtiles (V2 layout) via a 2-pass LDS transpose
// epilogue (reuses the 64KB As buffer; XOR'd rows keep u16x8 chunks contiguous).
__global__ __launch_bounds__(512, 2) void gemm_qkv_kernel(
    const u16* __restrict__ X, const u16* __restrict__ W, const float* __restrict__ bias,
    u16* __restrict__ Qb, u16* __restrict__ Kb, u16* __restrict__ V2) {
  __shared__ __align__(16) u16 As[2][2][128 * 64];   // [dbuf][mhalf][row*64+k]
  __shared__ __align__(16) u16 Bs[2][2][128 * 64];   // [dbuf][nhalf][row*64+k]
  const int tid = threadIdx.x;
  const int lane = tid & 63;
  const int wid = tid >> 6;
  const int wm = wid >> 2, wn = wid & 3;          // 2M x 4N wave grid
  const int g = lane >> 4, q15 = lane & 15;
  const int m0b = blockIdx.y * 256;
  const int n0b = blockIdx.x * 256;
  const int sA = 2 * ((q15 >> 2) & 1);            // read-side k-group XOR

  auto stageA = [&](int kt, int h) {
    #pragma unroll
    for (int it = 0; it < 2; ++it) {
      int c = it * 512 + tid;
      int row = c >> 3, kg = c & 7;
      int kgs = kg ^ (2 * ((row >> 2) & 1));      // pre-swizzled SOURCE
      gload16(X + (size_t)(m0b + h * 128 + row) * 1024 + kt * 64 + kgs * 8,
              &As[kt & 1][h][c * 8]);             // linear LDS dest
    }
  };
  auto stageB = [&](int kt, int h) {
    #pragma unroll
    for (int it = 0; it < 2; ++it) {
      int c = it * 512 + tid;
      int row = c >> 3, kg = c & 7;
      int kgs = kg ^ (2 * ((row >> 2) & 1));
      gload16(W + (size_t)(n0b + h * 128 + row) * 1024 + kt * 64 + kgs * 8,
              &Bs[kt & 1][h][c * 8]);
    }
  };

  f32x4 acc[8][4] = {};

  // ---- prologue: A(0), B(0), B(1); wait leaves B(1) in flight ----
  stageA(0, 0); stageA(0, 1);
  stageB(0, 0); stageB(0, 1);
  stageB(1, 0); stageB(1, 1);
  asm volatile("s_waitcnt vmcnt(4)" ::: "memory");
  __builtin_amdgcn_s_barrier();

  for (int kt = 0; kt < 16; ++kt) {
    const int d = kt & 1;
    const u16* Ah = As[d][wm];
    const u16* Bh = Bs[d][wn >> 1];
    const int rB0 = (wn & 1) * 64;
    bf16x8 bfr[4][2];
    #pragma unroll
    for (int q = 0; q < 4; ++q) {
      bf16x8 afr[2][2];
      if (q == 0) {                               // 8 B-frags, held across phases
        #pragma unroll
        for (int n = 0; n < 4; ++n)
          #pragma unroll
          for (int kk = 0; kk < 2; ++kk) {
            int row = rB0 + n * 16 + q15;
            int kg = (kk * 4 + g) ^ sA;
            bfr[n][kk] = *(const bf16x8*)(Bh + row * 64 + kg * 8);
          }
      }
      #pragma unroll
      for (int p = 0; p < 2; ++p)
        #pragma unroll
        for (int kk = 0; kk < 2; ++kk) {
          int row = (2 * q + p) * 16 + q15;
          int kg = (kk * 4 + g) ^ sA;
          afr[p][kk] = *(const bf16x8*)(Ah + row * 64 + kg * 8);
        }
      // stage one half-tile per phase
      if (q == 0)      { if (kt + 1 < 16) stageA(kt + 1, 0); }
      else if (q == 1) { if (kt + 1 < 16) stageA(kt + 1, 1); }
      else if (q == 2) { if (kt + 2 < 16) stageB(kt + 2, 0); }
      else             { if (kt + 2 < 16) stageB(kt + 2, 1); }
      __builtin_amdgcn_s_barrier();
      asm volatile("s_waitcnt lgkmcnt(0)" ::: "memory");
      __builtin_amdgcn_sched_barrier(0);
      __builtin_amdgcn_s_setprio(1);
      #pragma unroll
      for (int kk = 0; kk < 2; ++kk)
        #pragma unroll
        for (int p = 0; p < 2; ++p)
          #pragma unroll
          for (int n = 0; n < 4; ++n)
            acc[2 * q + p][n] = MFMA16(afr[p][kk], bfr[n][kk], acc[2 * q + p][n]);
      __builtin_amdgcn_s_setprio(0);
      if (q == 3) {                               // counted boundary wait
        if (kt < 14)       asm volatile("s_waitcnt vmcnt(4)" ::: "memory");
        else if (kt == 14) asm volatile("s_waitcnt vmcnt(0)" ::: "memory");
      }
      __builtin_amdgcn_s_barrier();
    }
  }

  const int which = n0b >> 10;                    // 0=Q 1=K 2=V (block-uniform)

  if (which < 2) {
    // ---- Q/K epilogue: bias (+Q-scale), direct scatter to [B,nh,C,64] ----
    const float qs = (which == 0) ? QSCALE : 1.0f;
    u16* __restrict__ dst = (which == 0) ? Qb : Kb;
    #pragma unroll
    for (int n = 0; n < 4; ++n) {
      int gcol = n0b + wn * 64 + n * 16 + q15;
      float bz = bias[gcol];
      int h = (gcol >> 6) & 15, d0 = gcol & 63;
      #pragma unroll
      for (int m = 0; m < 8; ++m)
        #pragma unroll
        for (int j = 0; j < 4; ++j) {
          int grow = m0b + wm * 128 + m * 16 + g * 4 + j;
          int bb = grow >> 11, qq = grow & 2047;
          dst[((size_t)((bb * 16 + h) * 2048 + qq)) * 64 + d0] =
              f2bf((acc[m][n][j] + bz) * qs);
        }
    }
  } else {
    // ---- V epilogue: 2-pass LDS transpose -> V2 [head][tile][d][key] ----
    u16* Ct = &As[0][0][0];                       // 64KB: [col 128][row 256]
    #pragma unroll
    for (int half = 0; half < 2; ++half) {
      __syncthreads();
      if ((wn >> 1) == half) {
        #pragma unroll
        for (int n = 0; n < 4; ++n) {
          int c = (wn & 1) * 64 + n * 16 + q15;   // col within half
          float bz = bias[n0b + half * 128 + c];
          #pragma unroll
          for (int m = 0; m < 8; ++m)
            #pragma unroll
            for (int j = 0; j < 4; ++j) {
              int r = wm * 128 + m * 16 + g * 4 + j;
              Ct[c * 256 + (r ^ ((c & 15) << 3))] = f2bf(acc[m][n][j] + bz);
            }
        }
      }
      __syncthreads();
      #pragma unroll
      for (int i = 0; i < 8; ++i) {
        int chunk = i * 512 + tid;
        int cc = chunk >> 5;                      // 0..127 (col within half)
        int r0 = (chunk & 31) * 8;                // 0..248
        u16x8 val = *(const u16x8*)(Ct + cc * 256 + (r0 ^ ((cc & 15) << 3)));
        int gcol = n0b + half * 128 + cc;
        int h = (gcol >> 6) & 15, d0 = gcol & 63;
        int grow = m0b + r0;
        int bb = grow >> 11, qq = grow & 2047;
        int tt = qq >> 6, key = qq & 63;
        *(u16x8*)(V2 + ((((size_t)(bb * 16 + h) * 32 + tt) * 64 + d0) * 64 + key)) = val;
      }
    }
  }
}

// ---------- GEMM2: out = attn @ Wo^T + b (fp32 out), 64x128 tile ----------
__global__ __launch_bounds__(256) void gemm_out_kernel(
    const u16* __restrict__ Ain, const u16* __restrict__ W, const float* __restrict__ bias,
    float* __restrict__ out) {
  __shared__ __align__(16) u16 As[64 * 64];
  __shared__ __align__(16) u16 Bs[128 * 64];
  const int tid = threadIdx.x;
  const int lane = tid & 63;
  const int wc = tid >> 6;                 // wave -> 32-col group
  const int m0 = blockIdx.y * 64;
  const int n0 = blockIdx.x * 128;
  f32x4 acc[4][2] = {};
  for (int k0 = 0; k0 < 1024; k0 += 64) {
    #pragma unroll
    for (int it = 0; it < 2; ++it) {
      int c = it * 256 + tid;
      gload16(Ain + (size_t)(m0 + (c >> 3)) * 1024 + k0 + ((c & 7) << 3), As + c * 8);
    }
    #pragma unroll
    for (int it = 0; it < 4; ++it) {
      int c = it * 256 + tid;
      gload16(W + (size_t)(n0 + (c >> 3)) * 1024 + k0 + ((c & 7) << 3), Bs + c * 8);
    }
    __syncthreads();
    #pragma unroll
    for (int kk = 0; kk < 2; ++kk) {
      bf16x8 a[4], b[2];
      #pragma unroll
      for (int m = 0; m < 4; ++m)
        a[m] = *(const bf16x8*)(As + ((m * 16 + (lane & 15)) * 64 +
                                      kk * 32 + ((lane >> 4) << 3)));
      #pragma unroll
      for (int n = 0; n < 2; ++n)
        b[n] = *(const bf16x8*)(Bs + ((wc * 32 + n * 16 + (lane & 15)) * 64 +
                                      kk * 32 + ((lane >> 4) << 3)));
      #pragma unroll
      for (int m = 0; m < 4; ++m)
        #pragma unroll
        for (int n = 0; n < 2; ++n)
          acc[m][n] = MFMA16(a[m], b[n], acc[m][n]);
    }
    __syncthreads();
  }
  #pragma unroll
  for (int m = 0; m < 4; ++m)
    #pragma unroll
    for (int n = 0; n < 2; ++n)
      #pragma unroll
      for (int j = 0; j < 4; ++j) {
        int row = m0 + m * 16 + ((lane >> 4) << 2) + j;
        int col = n0 + wc * 32 + n * 16 + (lane & 15);
        out[(size_t)row * 1024 + col] = acc[m][n][j] + bias[col];
      }
}

// ---------- causal flash attention: swapped-QK^T, in-register softmax & P ----------
// r12-verified body; V now staged from the V2 [d][key] subtiles via gload16
// with pre-swizzled source (IDENTICAL form to the proven K path) and read with
// the matching (d&7) XOR ds_read_b128. No scalar transpose, no reg staging.
__device__ __forceinline__ void attn_one(
    const u16* __restrict__ Qh, const u16* __restrict__ Kh, const u16* __restrict__ V2h,
    u16* __restrict__ Ob, int bb, int h, int qt,
    u16 (*Ks)[64 * 64], u16 (*Vs)[64 * 64]) {
  const int tid = threadIdx.x, lane = tid & 63, w = tid >> 6;
  const int g = lane >> 4, q15 = lane & 15;

  // Q fragment (B-operand): lane holds Q[qrow][kk*32 + 8g + i]
  bf16x8 qf[2];
  const int qrow = qt * 64 + w * 16 + q15;
  #pragma unroll
  for (int kk = 0; kk < 2; ++kk)
    qf[kk] = *(const bf16x8*)(Qh + (size_t)qrow * 64 + kk * 32 + g * 8);

  f32x4 acc_o[4];
  #pragma unroll
  for (int n = 0; n < 4; ++n) acc_o[n] = (f32x4){0.f, 0.f, 0.f, 0.f};
  float m_run = -INFINITY, l_run = 0.f;

  const int nt = qt + 1;

  auto stageK = [&](int t, int buf) {
    #pragma unroll
    for (int it = 0; it < 2; ++it) {
      int c = it * 256 + tid;
      int row = c >> 3, b8 = c & 7;
      gload16(Kh + (size_t)(t * 64 + row) * 64 + ((b8 ^ (row & 7)) << 3),
              Ks[buf] + c * 8);
    }
  };
  auto stageV = [&](int t, int buf) {    // V2: per-tile [d=64][key=64] contiguous
    #pragma unroll
    for (int it = 0; it < 2; ++it) {
      int c = it * 256 + tid;
      int row = c >> 3, b8 = c & 7;      // row = d
      gload16(V2h + (size_t)t * 4096 + row * 64 + ((b8 ^ (row & 7)) << 3),
              Vs[buf] + c * 8);
    }
  };

  // ---- prologue: tile 0 ----
  stageK(0, 0);
  stageV(0, 0);
  __syncthreads();

  for (int t = 0; t < nt; ++t) {
    const int cur = t & 1;
    const bool pre = (t + 1 < nt);
    if (pre) { stageK(t + 1, cur ^ 1); stageV(t + 1, cur ^ 1); }

    // ---- ST = K @ Q^T : lane holds P[q=q15][key = 16cb + 4g + j] ----
    f32x4 accs[4];
    __builtin_amdgcn_s_setprio(1);
    #pragma unroll
    for (int cb = 0; cb < 4; ++cb) {
      accs[cb] = (f32x4){0.f, 0.f, 0.f, 0.f};
      #pragma unroll
      for (int kk = 0; kk < 2; ++kk) {
        int row = cb * 16 + q15;
        int kblk = kk * 4 + g;
        bf16x8 kf = *(const bf16x8*)(Ks[cur] + row * 64 + ((kblk ^ (row & 7)) << 3));
        accs[cb] = MFMA16(kf, qf[kk], accs[cb]);
      }
    }
    __builtin_amdgcn_s_setprio(0);
    // causal mask on diagonal tile
    if (t == nt - 1) {
      #pragma unroll
      for (int cb = 0; cb < 4; ++cb)
        #pragma unroll
        for (int j = 0; j < 4; ++j) {
          int kg = t * 64 + cb * 16 + 4 * g + j;
          if (kg > qrow) accs[cb][j] = -INFINITY;
        }
    }

    // ---- online softmax (exp2 domain), lane-local q-row, T13 defer-max ----
    float mj = accs[0][0];
    #pragma unroll
    for (int cb = 0; cb < 4; ++cb)
      #pragma unroll
      for (int j = 0; j < 4; ++j) mj = fmaxf(mj, accs[cb][j]);
    mj = fmaxf(mj, __shfl_xor(mj, 16));
    mj = fmaxf(mj, __shfl_xor(mj, 32));
    if (!__all(mj - m_run <= 8.0f)) {
      float mn = fmaxf(m_run, mj);
      float sc = exp2f(m_run - mn);
      m_run = mn;
      l_run *= sc;
      float scj[4];
      #pragma unroll
      for (int j = 0; j < 4; ++j) scj[j] = __shfl(sc, 4 * g + j);
      #pragma unroll
      for (int n = 0; n < 4; ++n)
        #pragma unroll
        for (int j = 0; j < 4; ++j) acc_o[n][j] *= scj[j];
    }
    float rs = 0.f;
    #pragma unroll
    for (int cb = 0; cb < 4; ++cb)
      #pragma unroll
      for (int j = 0; j < 4; ++j) {
        float p = exp2f(accs[cb][j] - m_run);
        accs[cb][j] = p;
        rs += p;
      }
    rs += __shfl_xor(rs, 16);
    rs += __shfl_xor(rs, 32);
    l_run += rs;

    // ---- pack P to bf16 pairs: Wp[cb][hh] = keys (16cb+4g+2hh, +1) ----
    unsigned Wp[4][2];
    #pragma unroll
    for (int cb = 0; cb < 4; ++cb)
      #pragma unroll
      for (int hh = 0; hh < 2; ++hh)
        asm("v_cvt_pk_bf16_f32 %0, %1, %2"
            : "=v"(Wp[cb][hh]) : "v"(accs[cb][2 * hh]), "v"(accs[cb][2 * hh + 1]));

    // ---- exchange into PV A-fragments: lane needs keys kk*32+8g..+7 ----
    unsigned aw[2][4];
    #pragma unroll
    for (int kk = 0; kk < 2; ++kk)
      #pragma unroll
      for (int iw = 0; iw < 4; ++iw) {
        int srcLane = q15 + ((((g & 1) << 1) + (iw >> 1)) << 4);
        unsigned c0 = __shfl(Wp[2 * kk + 0][iw & 1], srcLane);
        unsigned c1 = __shfl(Wp[2 * kk + 1][iw & 1], srcLane);
        aw[kk][iw] = (g >> 1) ? c1 : c0;
      }
    bf16x8 pa0 = __builtin_bit_cast(bf16x8, (u32x4){aw[0][0], aw[0][1], aw[0][2], aw[0][3]});
    bf16x8 pa1 = __builtin_bit_cast(bf16x8, (u32x4){aw[1][0], aw[1][1], aw[1][2], aw[1][3]});

    // ---- O += P @ V  (V via K-style swizzled ds_read_b128 from V2 tile) ----
    __builtin_amdgcn_s_setprio(1);
    #pragma unroll
    for (int n = 0; n < 4; ++n) {
      #pragma unroll
      for (int kk = 0; kk < 2; ++kk) {
        int d = n * 16 + q15;
        int kblk = kk * 4 + g;
        bf16x8 vb = *(const bf16x8*)(Vs[cur] + d * 64 + ((kblk ^ (d & 7)) << 3));
        acc_o[n] = MFMA16(kk ? pa1 : pa0, vb, acc_o[n]);
      }
    }
    __builtin_amdgcn_s_setprio(0);
    __syncthreads();
  }

  // ---- epilogue: O /= l, write bf16 to [B*C, H] ----
  float invl = 1.0f / l_run;
  float invj[4];
  #pragma unroll
  for (int j = 0; j < 4; ++j) invj[j] = __shfl(invl, 4 * g + j);
  #pragma unroll
  for (int n = 0; n < 4; ++n)
    #pragma unroll
    for (int j = 0; j < 4; ++j) {
      int qg = qt * 64 + w * 16 + 4 * g + j;
      Ob[((size_t)(bb * 2048 + qg)) * 1024 + h * 64 + n * 16 + q15] =
          f2bf(acc_o[n][j] * invj[j]);
    }
}

// grid = 32 heads x 16 balanced pairs; block handles q-tiles (31-p, p): 33 KV tiles.
__global__ __launch_bounds__(256, 4) void attn_kernel(
    const u16* __restrict__ Qb, const u16* __restrict__ Kb, const u16* __restrict__ V2b,
    u16* __restrict__ Ob) {
  __shared__ __align__(16) u16 Ks[2][64 * 64];
  __shared__ __align__(16) u16 Vs[2][64 * 64];
  const int blk = blockIdx.x;
  const int p = blk & 15;
  const int bh = blk >> 4;             // 0..31 (b*16+h)
  const size_t base = (size_t)bh * 2048 * 64;   // 32 tiles * 4096 = 2048*64
  const int bb = bh >> 4, h = bh & 15;
  attn_one(Qb + base, Kb + base, V2b + base, Ob, bb, h, 31 - p, Ks, Vs);
  attn_one(Qb + base, Kb + base, V2b + base, Ob, bb, h, p, Ks, Vs);
}

// ---------- launch ----------
extern "C" void kernel_launch(void* const* d_in, const int* in_sizes, int n_in,
                              void* d_out, int out_size, void* d_ws, size_t ws_size,
                              hipStream_t stream) {
  const float* x    = (const float*)d_in[0];   // [2,2048,1024]
  const float* wqkv = (const float*)d_in[1];   // [3072,1024]
  const float* bqkv = (const float*)d_in[2];   // [3072]
  const float* wo   = (const float*)d_in[3];   // [1024,1024]
  const float* bo   = (const float*)d_in[4];   // [1024]
  float* out = (float*)d_out;                  // [4096,1024] fp32

  const size_t MB = 1u << 20;
  char* ws = (char*)d_ws;
  u16* x_bf  = (u16*)(ws);             // 8 MB
  u16* wq_bf = (u16*)(ws + 8 * MB);    // 6 MB
  u16* wo_bf = (u16*)(ws + 14 * MB);   // 2 MB
  u16* q_buf = (u16*)(ws + 16 * MB);   // 8 MB  [B,nh,C,64]
  u16* k_buf = (u16*)(ws + 24 * MB);   // 8 MB  [B,nh,C,64]
  u16* v2_buf= (u16*)(ws + 32 * MB);   // 8 MB  [B,nh,tile32,d64,key64]
  u16* a_out = (u16*)(ws + 40 * MB);   // 8 MB  [4096,1024]

  cast_all_kernel<<<8192, 256, 0, stream>>>(x, wqkv, wo, x_bf, wq_bf, wo_bf);

  gemm_qkv_kernel<<<dim3(12, 16), 512, 0, stream>>>(x_bf, wq_bf, bqkv,
                                                    q_buf, k_buf, v2_buf);
  attn_kernel<<<512, 256, 0, stream>>>(q_buf, k_buf, v2_buf, a_out);
  gemm_out_kernel<<<dim3(8, 64), 256, 0, stream>>>(a_out, wo_bf, bo, out);
}

// Round 18
// 131.872 us; speedup vs baseline: 1.1508x; 1.0215x over previous
//
#include <hip/hip_runtime.h>
#include <hip/hip_bf16.h>
#include <math.h>

typedef unsigned short u16;
typedef __attribute__((ext_vector_type(8))) __bf16 bf16x8;
typedef __attribute__((ext_vector_type(4))) float f32x4;
typedef __attribute__((ext_vector_type(8))) unsigned short u16x8;
typedef __attribute__((ext_vector_type(4))) unsigned int u32x4;

// ---------- helpers ----------
__device__ __forceinline__ u16 f2bf(float f) {
  union { float f; unsigned u; } x; x.f = f;
  unsigned r = x.u + 0x7fffu + ((x.u >> 16) & 1u);   // RNE
  return (u16)(r >> 16);
}

__device__ __forceinline__ void gload16(const u16* g, u16* l) {
  __builtin_amdgcn_global_load_lds(
      (const __attribute__((address_space(1))) void*)g,
      (__attribute__((address_space(3))) void*)l, 16, 0, 0);
}

#define MFMA16(a, b, c) __builtin_amdgcn_mfma_f32_16x16x32_bf16((a), (b), (c), 0, 0, 0)

// Q pre-scale: 1/sqrt(64) * log2(e)  (softmax done in exp2 domain)
#define QSCALE 0.18033688011112043f

// ---------- merged cast fp32 -> bf16 (x, Wqkv, Wo in one launch) ----------
__global__ __launch_bounds__(256) void cast_all_kernel(
    const float* __restrict__ x, const float* __restrict__ wqkv,
    const float* __restrict__ wo, u16* __restrict__ xb,
    u16* __restrict__ wqb, u16* __restrict__ wob) {
  int i = blockIdx.x * 256 + threadIdx.x;   // in float4 units
  const float* src; u16* dst;
  if (i < 1048576)      { src = x;    dst = xb;  }
  else if (i < 1835008) { src = wqkv; dst = wqb; i -= 1048576; }
  else                  { src = wo;   dst = wob; i -= 1835008; }
  f32x4 v = *(const f32x4*)(src + (size_t)i * 4);
  u16 o0 = f2bf(v[0]), o1 = f2bf(v[1]), o2 = f2bf(v[2]), o3 = f2bf(v[3]);
  unsigned lo = (unsigned)o0 | ((unsigned)o1 << 16);
  unsigned hi = (unsigned)o2 | ((unsigned)o3 << 16);
  ((unsigned*)dst)[(size_t)i * 2] = lo;
  ((unsigned*)dst)[(size_t)i * 2 + 1] = hi;
}

// ---------- GEMM1: 256x256 tile, BK=64, 8 waves, 8-phase counted-vmcnt ----------
// 3-bit LDS swizzle (attn-proven form): source kg ^= (row&7); reads use
// kg = (kk*4+g) ^ (q15&7) since all read rows have row&7 == q15&7.
__global__ __launch_bounds__(512, 2) void gemm_qkv_kernel(
    const u16* __restrict__ X, const u16* __restrict__ W, const float* __restrict__ bias,
    u16* __restrict__ Qb, u16* __restrict__ Kb, u16* __restrict__ V2) {
  __shared__ __align__(16) u16 As[2][2][128 * 64];   // [dbuf][mhalf][row*64+k]
  __shared__ __align__(16) u16 Bs[2][2][128 * 64];   // [dbuf][nhalf][row*64+k]
  const int tid = threadIdx.x;
  const int lane = tid & 63;
  const int wid = tid >> 6;
  const int wm = wid >> 2, wn = wid & 3;          // 2M x 4N wave grid
  const int g = lane >> 4, q15 = lane & 15;
  const int m0b = blockIdx.y * 256;
  const int n0b = blockIdx.x * 256;
  const int sA = q15 & 7;                         // read-side 3-bit k-group XOR

  auto stageA = [&](int kt, int h) {
    #pragma unroll
    for (int it = 0; it < 2; ++it) {
      int c = it * 512 + tid;
      int row = c >> 3, kg = c & 7;
      int kgs = kg ^ (row & 7);                   // pre-swizzled SOURCE
      gload16(X + (size_t)(m0b + h * 128 + row) * 1024 + kt * 64 + kgs * 8,
              &As[kt & 1][h][c * 8]);             // linear LDS dest
    }
  };
  auto stageB = [&](int kt, int h) {
    #pragma unroll
    for (int it = 0; it < 2; ++it) {
      int c = it * 512 + tid;
      int row = c >> 3, kg = c & 7;
      int kgs = kg ^ (row & 7);
      gload16(W + (size_t)(n0b + h * 128 + row) * 1024 + kt * 64 + kgs * 8,
              &Bs[kt & 1][h][c * 8]);
    }
  };

  f32x4 acc[8][4] = {};

  // ---- prologue: A(0), B(0), B(1); wait leaves B(1) in flight ----
  stageA(0, 0); stageA(0, 1);
  stageB(0, 0); stageB(0, 1);
  stageB(1, 0); stageB(1, 1);
  asm volatile("s_waitcnt vmcnt(4)" ::: "memory");
  __builtin_amdgcn_s_barrier();

  for (int kt = 0; kt < 16; ++kt) {
    const int d = kt & 1;
    const u16* Ah = As[d][wm];
    const u16* Bh = Bs[d][wn >> 1];
    const int rB0 = (wn & 1) * 64;
    bf16x8 bfr[4][2];
    #pragma unroll
    for (int q = 0; q < 4; ++q) {
      bf16x8 afr[2][2];
      if (q == 0) {                               // 8 B-frags, held across phases
        #pragma unroll
        for (int n = 0; n < 4; ++n)
          #pragma unroll
          for (int kk = 0; kk < 2; ++kk) {
            int row = rB0 + n * 16 + q15;
            int kg = (kk * 4 + g) ^ sA;
            bfr[n][kk] = *(const bf16x8*)(Bh + row * 64 + kg * 8);
          }
      }
      #pragma unroll
      for (int p = 0; p < 2; ++p)
        #pragma unroll
        for (int kk = 0; kk < 2; ++kk) {
          int row = (2 * q + p) * 16 + q15;
          int kg = (kk * 4 + g) ^ sA;
          afr[p][kk] = *(const bf16x8*)(Ah + row * 64 + kg * 8);
        }
      // stage one half-tile per phase
      if (q == 0)      { if (kt + 1 < 16) stageA(kt + 1, 0); }
      else if (q == 1) { if (kt + 1 < 16) stageA(kt + 1, 1); }
      else if (q == 2) { if (kt + 2 < 16) stageB(kt + 2, 0); }
      else             { if (kt + 2 < 16) stageB(kt + 2, 1); }
      __builtin_amdgcn_s_barrier();
      asm volatile("s_waitcnt lgkmcnt(0)" ::: "memory");
      __builtin_amdgcn_sched_barrier(0);
      __builtin_amdgcn_s_setprio(1);
      #pragma unroll
      for (int kk = 0; kk < 2; ++kk)
        #pragma unroll
        for (int p = 0; p < 2; ++p)
          #pragma unroll
          for (int n = 0; n < 4; ++n)
            acc[2 * q + p][n] = MFMA16(afr[p][kk], bfr[n][kk], acc[2 * q + p][n]);
      __builtin_amdgcn_s_setprio(0);
      if (q == 3) {                               // counted boundary wait
        if (kt < 14)       asm volatile("s_waitcnt vmcnt(4)" ::: "memory");
        else if (kt == 14) asm volatile("s_waitcnt vmcnt(0)" ::: "memory");
      }
      __builtin_amdgcn_s_barrier();
    }
  }

  const int which = n0b >> 10;                    // 0=Q 1=K 2=V (block-uniform)

  if (which < 2) {
    // ---- Q/K epilogue: bias (+Q-scale), direct scatter to [B,nh,C,64] ----
    const float qs = (which == 0) ? QSCALE : 1.0f;
    u16* __restrict__ dst = (which == 0) ? Qb : Kb;
    #pragma unroll
    for (int n = 0; n < 4; ++n) {
      int gcol = n0b + wn * 64 + n * 16 + q15;
      float bz = bias[gcol];
      int h = (gcol >> 6) & 15, d0 = gcol & 63;
      #pragma unroll
      for (int m = 0; m < 8; ++m)
        #pragma unroll
        for (int j = 0; j < 4; ++j) {
          int grow = m0b + wm * 128 + m * 16 + g * 4 + j;
          int bb = grow >> 11, qq = grow & 2047;
          dst[((size_t)((bb * 16 + h) * 2048 + qq)) * 64 + d0] =
              f2bf((acc[m][n][j] + bz) * qs);
        }
    }
  } else {
    // ---- V epilogue: 2-pass LDS transpose -> V2 [head][tile][d][key] ----
    u16* Ct = &As[0][0][0];                       // 64KB: [col 128][row 256]
    #pragma unroll
    for (int half = 0; half < 2; ++half) {
      __syncthreads();
      if ((wn >> 1) == half) {
        #pragma unroll
        for (int n = 0; n < 4; ++n) {
          int c = (wn & 1) * 64 + n * 16 + q15;   // col within half
          float bz = bias[n0b + half * 128 + c];
          #pragma unroll
          for (int m = 0; m < 8; ++m)
            #pragma unroll
            for (int j = 0; j < 4; ++j) {
              int r = wm * 128 + m * 16 + g * 4 + j;
              Ct[c * 256 + (r ^ ((c & 15) << 3))] = f2bf(acc[m][n][j] + bz);
            }
        }
      }
      __syncthreads();
      #pragma unroll
      for (int i = 0; i < 8; ++i) {
        int chunk = i * 512 + tid;
        int cc = chunk >> 5;                      // 0..127 (col within half)
        int r0 = (chunk & 31) * 8;                // 0..248
        u16x8 val = *(const u16x8*)(Ct + cc * 256 + (r0 ^ ((cc & 15) << 3)));
        int gcol = n0b + half * 128 + cc;
        int h = (gcol >> 6) & 15, d0 = gcol & 63;
        int grow = m0b + r0;
        int bb = grow >> 11, qq = grow & 2047;
        int tt = qq >> 6, key = qq & 63;
        *(u16x8*)(V2 + ((((size_t)(bb * 16 + h) * 32 + tt) * 64 + d0) * 64 + key)) = val;
      }
    }
  }
}

// ---------- GEMM2: out = attn @ Wo^T + b (fp32), 64x128 tile, dbuf 1-barrier ----------
__global__ __launch_bounds__(256) void gemm_out_kernel(
    const u16* __restrict__ Ain, const u16* __restrict__ W, const float* __restrict__ bias,
    float* __restrict__ out) {
  __shared__ __align__(16) u16 As[2][64 * 64];
  __shared__ __align__(16) u16 Bs[2][128 * 64];
  const int tid = threadIdx.x;
  const int lane = tid & 63;
  const int wc = tid >> 6;                 // wave -> 32-col group
  const int m0 = blockIdx.y * 64;
  const int n0 = blockIdx.x * 128;

  auto stage = [&](int k0, int buf) {
    #pragma unroll
    for (int it = 0; it < 2; ++it) {
      int c = it * 256 + tid;
      gload16(Ain + (size_t)(m0 + (c >> 3)) * 1024 + k0 + ((c & 7) << 3),
              As[buf] + c * 8);
    }
    #pragma unroll
    for (int it = 0; it < 4; ++it) {
      int c = it * 256 + tid;
      gload16(W + (size_t)(n0 + (c >> 3)) * 1024 + k0 + ((c & 7) << 3),
              Bs[buf] + c * 8);
    }
  };

  f32x4 acc[4][2] = {};
  stage(0, 0);
  __syncthreads();
  for (int k0 = 0; k0 < 1024; k0 += 64) {
    const int cur = (k0 >> 6) & 1;
    if (k0 + 64 < 1024) stage(k0 + 64, cur ^ 1);   // issue-early; overlaps compute
    #pragma unroll
    for (int kk = 0; kk < 2; ++kk) {
      bf16x8 a[4], b[2];
      #pragma unroll
      for (int m = 0; m < 4; ++m)
        a[m] = *(const bf16x8*)(As[cur] + ((m * 16 + (lane & 15)) * 64 +
                                           kk * 32 + ((lane >> 4) << 3)));
      #pragma unroll
      for (int n = 0; n < 2; ++n)
        b[n] = *(const bf16x8*)(Bs[cur] + ((wc * 32 + n * 16 + (lane & 15)) * 64 +
                                           kk * 32 + ((lane >> 4) << 3)));
      __builtin_amdgcn_s_setprio(1);
      #pragma unroll
      for (int m = 0; m < 4; ++m)
        #pragma unroll
        for (int n = 0; n < 2; ++n)
          acc[m][n] = MFMA16(a[m], b[n], acc[m][n]);
      __builtin_amdgcn_s_setprio(0);
    }
    __syncthreads();   // drains next-stage DMA (issued before compute)
  }
  #pragma unroll
  for (int m = 0; m < 4; ++m)
    #pragma unroll
    for (int n = 0; n < 2; ++n)
      #pragma unroll
      for (int j = 0; j < 4; ++j) {
        int row = m0 + m * 16 + ((lane >> 4) << 2) + j;
        int col = n0 + wc * 32 + n * 16 + (lane & 15);
        out[(size_t)row * 1024 + col] = acc[m][n][j] + bias[col];
      }
}

// ---------- causal flash attention: swapped-QK^T, in-register softmax & P ----------
// r17-verified body (61.5 us): V from V2 [d][key] subtiles via K-style path.
__device__ __forceinline__ void attn_one(
    const u16* __restrict__ Qh, const u16* __restrict__ Kh, const u16* __restrict__ V2h,
    u16* __restrict__ Ob, int bb, int h, int qt,
    u16 (*Ks)[64 * 64], u16 (*Vs)[64 * 64]) {
  const int tid = threadIdx.x, lane = tid & 63, w = tid >> 6;
  const int g = lane >> 4, q15 = lane & 15;

  // Q fragment (B-operand): lane holds Q[qrow][kk*32 + 8g + i]
  bf16x8 qf[2];
  const int qrow = qt * 64 + w * 16 + q15;
  #pragma unroll
  for (int kk = 0; kk < 2; ++kk)
    qf[kk] = *(const bf16x8*)(Qh + (size_t)qrow * 64 + kk * 32 + g * 8);

  f32x4 acc_o[4];
  #pragma unroll
  for (int n = 0; n < 4; ++n) acc_o[n] = (f32x4){0.f, 0.f, 0.f, 0.f};
  float m_run = -INFINITY, l_run = 0.f;

  const int nt = qt + 1;

  auto stageK = [&](int t, int buf) {
    #pragma unroll
    for (int it = 0; it < 2; ++it) {
      int c = it * 256 + tid;
      int row = c >> 3, b8 = c & 7;
      gload16(Kh + (size_t)(t * 64 + row) * 64 + ((b8 ^ (row & 7)) << 3),
              Ks[buf] + c * 8);
    }
  };
  auto stageV = [&](int t, int buf) {    // V2: per-tile [d=64][key=64] contiguous
    #pragma unroll
    for (int it = 0; it < 2; ++it) {
      int c = it * 256 + tid;
      int row = c >> 3, b8 = c & 7;      // row = d
      gload16(V2h + (size_t)t * 4096 + row * 64 + ((b8 ^ (row & 7)) << 3),
              Vs[buf] + c * 8);
    }
  };

  // ---- prologue: tile 0 ----
  stageK(0, 0);
  stageV(0, 0);
  __syncthreads();

  for (int t = 0; t < nt; ++t) {
    const int cur = t & 1;
    const bool pre = (t + 1 < nt);
    if (pre) { stageK(t + 1, cur ^ 1); stageV(t + 1, cur ^ 1); }

    // ---- ST = K @ Q^T : lane holds P[q=q15][key = 16cb + 4g + j] ----
    f32x4 accs[4];
    __builtin_amdgcn_s_setprio(1);
    #pragma unroll
    for (int cb = 0; cb < 4; ++cb) {
      accs[cb] = (f32x4){0.f, 0.f, 0.f, 0.f};
      #pragma unroll
      for (int kk = 0; kk < 2; ++kk) {
        int row = cb * 16 + q15;
        int kblk = kk * 4 + g;
        bf16x8 kf = *(const bf16x8*)(Ks[cur] + row * 64 + ((kblk ^ (row & 7)) << 3));
        accs[cb] = MFMA16(kf, qf[kk], accs[cb]);
      }
    }
    __builtin_amdgcn_s_setprio(0);
    // causal mask on diagonal tile
    if (t == nt - 1) {
      #pragma unroll
      for (int cb = 0; cb < 4; ++cb)
        #pragma unroll
        for (int j = 0; j < 4; ++j) {
          int kg = t * 64 + cb * 16 + 4 * g + j;
          if (kg > qrow) accs[cb][j] = -INFINITY;
        }
    }

    // ---- online softmax (exp2 domain), lane-local q-row, T13 defer-max ----
    float mj = accs[0][0];
    #pragma unroll
    for (int cb = 0; cb < 4; ++cb)
      #pragma unroll
      for (int j = 0; j < 4; ++j) mj = fmaxf(mj, accs[cb][j]);
    mj = fmaxf(mj, __shfl_xor(mj, 16));
    mj = fmaxf(mj, __shfl_xor(mj, 32));
    if (!__all(mj - m_run <= 8.0f)) {
      float mn = fmaxf(m_run, mj);
      float sc = exp2f(m_run - mn);
      m_run = mn;
      l_run *= sc;
      float scj[4];
      #pragma unroll
      for (int j = 0; j < 4; ++j) scj[j] = __shfl(sc, 4 * g + j);
      #pragma unroll
      for (int n = 0; n < 4; ++n)
        #pragma unroll
        for (int j = 0; j < 4; ++j) acc_o[n][j] *= scj[j];
    }
    float rs = 0.f;
    #pragma unroll
    for (int cb = 0; cb < 4; ++cb)
      #pragma unroll
      for (int j = 0; j < 4; ++j) {
        float p = exp2f(accs[cb][j] - m_run);
        accs[cb][j] = p;
        rs += p;
      }
    rs += __shfl_xor(rs, 16);
    rs += __shfl_xor(rs, 32);
    l_run += rs;

    // ---- pack P to bf16 pairs: Wp[cb][hh] = keys (16cb+4g+2hh, +1) ----
    unsigned Wp[4][2];
    #pragma unroll
    for (int cb = 0; cb < 4; ++cb)
      #pragma unroll
      for (int hh = 0; hh < 2; ++hh)
        asm("v_cvt_pk_bf16_f32 %0, %1, %2"
            : "=v"(Wp[cb][hh]) : "v"(accs[cb][2 * hh]), "v"(accs[cb][2 * hh + 1]));

    // ---- exchange into PV A-fragments: lane needs keys kk*32+8g..+7 ----
    unsigned aw[2][4];
    #pragma unroll
    for (int kk = 0; kk < 2; ++kk)
      #pragma unroll
      for (int iw = 0; iw < 4; ++iw) {
        int srcLane = q15 + ((((g & 1) << 1) + (iw >> 1)) << 4);
        unsigned c0 = __shfl(Wp[2 * kk + 0][iw & 1], srcLane);
        unsigned c1 = __shfl(Wp[2 * kk + 1][iw & 1], srcLane);
        aw[kk][iw] = (g >> 1) ? c1 : c0;
      }
    bf16x8 pa0 = __builtin_bit_cast(bf16x8, (u32x4){aw[0][0], aw[0][1], aw[0][2], aw[0][3]});
    bf16x8 pa1 = __builtin_bit_cast(bf16x8, (u32x4){aw[1][0], aw[1][1], aw[1][2], aw[1][3]});

    // ---- O += P @ V  (V via K-style swizzled ds_read_b128 from V2 tile) ----
    __builtin_amdgcn_s_setprio(1);
    #pragma unroll
    for (int n = 0; n < 4; ++n) {
      #pragma unroll
      for (int kk = 0; kk < 2; ++kk) {
        int d = n * 16 + q15;
        int kblk = kk * 4 + g;
        bf16x8 vb = *(const bf16x8*)(Vs[cur] + d * 64 + ((kblk ^ (d & 7)) << 3));
        acc_o[n] = MFMA16(kk ? pa1 : pa0, vb, acc_o[n]);
      }
    }
    __builtin_amdgcn_s_setprio(0);
    __syncthreads();
  }

  // ---- epilogue: O /= l, write bf16 to [B*C, H] ----
  float invl = 1.0f / l_run;
  float invj[4];
  #pragma unroll
  for (int j = 0; j < 4; ++j) invj[j] = __shfl(invl, 4 * g + j);
  #pragma unroll
  for (int n = 0; n < 4; ++n)
    #pragma unroll
    for (int j = 0; j < 4; ++j) {
      int qg = qt * 64 + w * 16 + 4 * g + j;
      Ob[((size_t)(bb * 2048 + qg)) * 1024 + h * 64 + n * 16 + q15] =
          f2bf(acc_o[n][j] * invj[j]);
    }
}

// grid = 32 heads x 16 balanced pairs; block handles q-tiles (31-p, p): 33 KV tiles.
__global__ __launch_bounds__(256, 4) void attn_kernel(
    const u16* __restrict__ Qb, const u16* __restrict__ Kb, const u16* __restrict__ V2b,
    u16* __restrict__ Ob) {
  __shared__ __align__(16) u16 Ks[2][64 * 64];
  __shared__ __align__(16) u16 Vs[2][64 * 64];
  const int blk = blockIdx.x;
  const int p = blk & 15;
  const int bh = blk >> 4;             // 0..31 (b*16+h)
  const size_t base = (size_t)bh * 2048 * 64;   // 32 tiles * 4096 = 2048*64
  const int bb = bh >> 4, h = bh & 15;
  attn_one(Qb + base, Kb + base, V2b + base, Ob, bb, h, 31 - p, Ks, Vs);
  attn_one(Qb + base, Kb + base, V2b + base, Ob, bb, h, p, Ks, Vs);
}

// ---------- launch ----------
extern "C" void kernel_launch(void* const* d_in, const int* in_sizes, int n_in,
                              void* d_out, int out_size, void* d_ws, size_t ws_size,
                              hipStream_t stream) {
  const float* x    = (const float*)d_in[0];   // [2,2048,1024]
  const float* wqkv = (const float*)d_in[1];   // [3072,1024]
  const float* bqkv = (const float*)d_in[2];   // [3072]
  const float* wo   = (const float*)d_in[3];   // [1024,1024]
  const float* bo   = (const float*)d_in[4];   // [1024]
  float* out = (float*)d_out;                  // [4096,1024] fp32

  const size_t MB = 1u << 20;
  char* ws = (char*)d_ws;
  u16* x_bf  = (u16*)(ws);             // 8 MB
  u16* wq_bf = (u16*)(ws + 8 * MB);    // 6 MB
  u16* wo_bf = (u16*)(ws + 14 * MB);   // 2 MB
  u16* q_buf = (u16*)(ws + 16 * MB);   // 8 MB  [B,nh,C,64]
  u16* k_buf = (u16*)(ws + 24 * MB);   // 8 MB  [B,nh,C,64]
  u16* v2_buf= (u16*)(ws + 32 * MB);   // 8 MB  [B,nh,tile32,d64,key64]
  u16* a_out = (u16*)(ws + 40 * MB);   // 8 MB  [4096,1024]

  cast_all_kernel<<<8192, 256, 0, stream>>>(x, wqkv, wo, x_bf, wq_bf, wo_bf);

  gemm_qkv_kernel<<<dim3(12, 16), 512, 0, stream>>>(x_bf, wq_bf, bqkv,
                                                    q_buf, k_buf, v2_buf);
  attn_kernel<<<512, 256, 0, stream>>>(q_buf, k_buf, v2_buf, a_out);
  gemm_out_kernel<<<dim3(8, 64), 256, 0, stream>>>(a_out, wo_bf, bo, out);
}